// Round 5
// baseline (962.856 us; speedup 1.0000x reference)
//
#include <hip/hip_runtime.h>
#include <hip/hip_bf16.h>

#define BB 512
#define NA 58
#define LAT 64
#define HID 128
#define AF 10
#define NL 2
#define NN (BB*NA)      // 29696
#define NE (NN*16)      // 475136
#define ET 64           // edges per chunk
#define RPB 29          // rows per block (NN = 29*1024)
#define NBLK (NN/RPB)   // 1024

typedef __attribute__((ext_vector_type(8))) short s8;
typedef __attribute__((ext_vector_type(4))) float f4;

struct CvtDesc {
    const void* src[24];
    float*      dst[24];
    int         len[24];
};

struct PackJobs {
    const float* src[11];
    short*       dst[11];
    int          K[11];
    int          mode[11];   // 0: [K][128] B-frag; 1: edge-w1 concat; 2: [K][64] B-frag
};

__device__ __forceinline__ float siluf(float x) {
    return x * __builtin_amdgcn_rcpf(1.0f + __expf(-x));
}

__device__ __forceinline__ short f2b(float x) {
    __hip_bfloat16 b = __float2bfloat16(x);
    return *(short*)&b;
}

__device__ __forceinline__ float b2f(short s) {
    return __uint_as_float(((unsigned int)(unsigned short)s) << 16);
}

// ---------------------------------------------------------------------------
__global__ void k_detect(const unsigned short* __restrict__ z16,
                         const unsigned int* __restrict__ e32,
                         int* __restrict__ flags) {
    __shared__ int sbf, si64;
    if (threadIdx.x == 0) { sbf = 0; si64 = 0; }
    __syncthreads();
    int c1 = 0, c2 = 0;
    for (int i = threadIdx.x; i < 1024; i += 256) {
        unsigned short v = z16[2*i];
        int e = (v >> 7) & 0xFF;
        if (e >= 100 && e <= 140) c1++;
        if (e32[2*i + 1] == 0u) c2++;
    }
    atomicAdd(&sbf, c1);
    atomicAdd(&si64, c2);
    __syncthreads();
    if (threadIdx.x == 0) {
        flags[0] = (sbf  > 600) ? 1 : 0;
        flags[1] = (si64 > 600) ? 1 : 0;
    }
}

__global__ void k_convert(CvtDesc d, const int* __restrict__ flags) {
    int a = blockIdx.y;
    int i = blockIdx.x * blockDim.x + threadIdx.x;
    int n = d.len[a];
    if (i >= n) return;
    if (flags[0]) {
        d.dst[a][i] = __bfloat162float(((const __hip_bfloat16*)d.src[a])[i]);
    } else {
        d.dst[a][i] = ((const float*)d.src[a])[i];
    }
}

__global__ void k_packall(PackJobs pj) {
    int j = blockIdx.y;
    int idx = blockIdx.x * 256 + threadIdx.x;
    const float* w = pj.src[j];
    short* o = pj.dst[j];
    int mode = pj.mode[j];
    if (mode == 0) {
        int K = pj.K[j];
        if (idx >= 128*K) return;
        int jj = idx & 7;
        int l  = (idx >> 3) & 63;
        int rest = idx >> 9;
        int KC = K >> 5;
        int kc = rest % KC;
        int nt = rest / KC;
        int n = nt*16 + (l & 15);
        int k = kc*32 + (l >> 4)*8 + jj;
        o[idx] = f2b(w[k*128 + n]);
    } else if (mode == 1) {
        if (idx >= 32768) return;
        int jj = idx & 7;
        int l  = (idx >> 3) & 63;
        int rest = idx >> 9;
        int kc = rest & 3;
        int nt = rest >> 2;
        int n = nt*16 + (l & 15);
        int k = kc*32 + (l >> 4)*8 + jj;
        float v = (n < 128) ? w[k*128 + n] : w[(128 + k)*128 + (n - 128)];
        o[idx] = f2b(v);
    } else {
        if (idx >= 8192) return;
        int jj = idx & 7;
        int l  = (idx >> 3) & 63;
        int rest = idx >> 9;
        int kc = rest & 3;
        int nt = rest >> 2;
        int n = nt*16 + (l & 15);
        int k = kc*32 + (l >> 4)*8 + jj;
        o[idx] = f2b(w[k*64 + n]);
    }
}

// ---------------------------------------------------------------------------
__global__ void k_hist(const int* __restrict__ eidx, const int* __restrict__ flags,
                       int* __restrict__ cnt) {
    int e = blockIdx.x * 256 + threadIdx.x;
    if (e >= NE) return;
    int is64 = flags[1];
    int r = eidx[is64 ? 2*(long)e : (long)e];
    atomicAdd(&cnt[r], 1);
}

__global__ __launch_bounds__(1024) void k_scan(const int* __restrict__ cnt,
                                               int* __restrict__ rowStart,
                                               int* __restrict__ cursor) {
    __shared__ int part[1024];
    int t = threadIdx.x;
    int base = t * 29;                    // NN == 1024*29
    int loc[29];
    int s = 0;
    #pragma unroll
    for (int i = 0; i < 29; ++i) { loc[i] = s; s += cnt[base + i]; }
    part[t] = s;
    __syncthreads();
    for (int d = 1; d < 1024; d <<= 1) {
        int v = (t >= d) ? part[t - d] : 0;
        __syncthreads();
        part[t] += v;
        __syncthreads();
    }
    int pre = (t == 0) ? 0 : part[t - 1];
    #pragma unroll
    for (int i = 0; i < 29; ++i) {
        int v = pre + loc[i];
        rowStart[base + i] = v;
        cursor[base + i] = v;
    }
    if (t == 1023) rowStart[NN] = pre + s;
}

__global__ void k_scatter(const int* __restrict__ eidx, const int* __restrict__ flags,
                          int* __restrict__ cursor,
                          int* __restrict__ rS, int* __restrict__ cS) {
    int e = blockIdx.x * 256 + threadIdx.x;
    if (e >= NE) return;
    int is64 = flags[1];
    long ge = e, gc = (long)e + NE;
    int r = eidx[is64 ? 2*ge : ge];
    int c = eidx[is64 ? 2*gc : gc];
    int p = atomicAdd(&cursor[r], 1);
    rS[p] = r; cS[p] = c;
}

// ---------------------------------------------------------------------------
// init3: fused hz GEMV + h init (bf16) + pos init + zero agg/upd + H1(l0) GEMM.
__global__ __launch_bounds__(256) void k_init3(
    const float* __restrict__ z, const float* __restrict__ lw,
    const float* __restrict__ lbz,
    const float* __restrict__ at,
    const float* __restrict__ aw, const float* __restrict__ ab,
    const float* __restrict__ ic,
    float* __restrict__ pos, short* __restrict__ hb,
    const short* __restrict__ wcat0, const float* __restrict__ b10,
    short* __restrict__ H1, float* __restrict__ agg, float* __restrict__ upd)
{
    __shared__ short x[64][136];
    __shared__ float awS[AF][HID];
    __shared__ float atS[64][AF+2];
    __shared__ float zbS[3][LAT];
    __shared__ float hzS[3][HID];
    const int tid = threadIdx.x;
    const int n0 = blockIdx.x * 64;
    const int b0 = n0 / NA;
    const int nb = (n0 + 63) / NA - b0 + 1;   // 1..3

    for (int i = tid; i < AF*HID; i += 256) awS[i/HID][i%HID] = aw[i];
    for (int i = tid; i < 64*AF; i += 256)
        atS[i/AF][i%AF] = at[(long)(n0 + i/AF)*AF + i%AF];
    for (int i = tid; i < nb*LAT; i += 256) {
        int bi = i / LAT, k = i - bi*LAT;
        int bidx = b0 + bi;
        zbS[bi][k] = (bidx < BB) ? z[bidx*LAT + k] : 0.f;
    }
    __syncthreads();

    for (int i = tid; i < nb*HID; i += 256) {
        int bi = i / HID, c = i - bi*HID;
        float acc = lbz[c];
        #pragma unroll
        for (int k = 0; k < LAT; ++k) acc += zbS[bi][k] * lw[k*HID + c];
        hzS[bi][c] = acc;
    }
    __syncthreads();

    #pragma unroll
    for (int it = 0; it < 32; ++it) {
        int idx = it*256 + tid;
        int r = idx >> 7, c = idx & 127;
        int n = n0 + r;
        float v = hzS[n/NA - b0][c] + ab[c];
        #pragma unroll
        for (int f = 0; f < AF; ++f) v += atS[r][f]*awS[f][c];
        short s = f2b(v);
        x[r][c] = s;
        hb[(long)n*HID + c] = s;
    }
    if (tid < 192) {
        int i = tid/3, d = tid - i*3;
        int n = n0 + i;
        pos[n*3 + d] = ic[(n % NA)*3 + d];
        upd[n*3 + d] = 0.f;
    }
    {
        f4* a4 = (f4*)(agg + (long)n0*HID);
        for (int j = tid; j < 64*HID/4; j += 256) a4[j] = (f4)0.f;
    }
    __syncthreads();

    const int l = tid & 63, w = tid >> 6;
    const int l16 = l & 15, quad = l >> 4;
    f4 acc[4][4];
    #pragma unroll
    for (int mt = 0; mt < 4; ++mt)
        #pragma unroll
        for (int nt4 = 0; nt4 < 4; ++nt4) acc[mt][nt4] = (f4)0.f;
    #pragma unroll
    for (int kc = 0; kc < 4; ++kc) {
        s8 a[4];
        #pragma unroll
        for (int mt = 0; mt < 4; ++mt)
            a[mt] = *(const s8*)&x[mt*16 + l16][kc*32 + quad*8];
        #pragma unroll
        for (int nt4 = 0; nt4 < 4; ++nt4) {
            int nt = w*4 + nt4;
            s8 b = *(const s8*)(wcat0 + (((size_t)nt*4 + kc)*64 + l)*8);
            #pragma unroll
            for (int mt = 0; mt < 4; ++mt)
                acc[mt][nt4] = __builtin_amdgcn_mfma_f32_16x16x32_bf16(a[mt], b, acc[mt][nt4], 0, 0, 0);
        }
    }
    #pragma unroll
    for (int nt4 = 0; nt4 < 4; ++nt4) {
        int col = (w*4 + nt4)*16 + l16;
        float bias = (col < 128) ? b10[col] : 0.f;
        #pragma unroll
        for (int mt = 0; mt < 4; ++mt)
            #pragma unroll
            for (int i = 0; i < 4; ++i) {
                int row = mt*16 + quad*4 + i;
                H1[(long)(n0 + row)*256 + col] = f2b(acc[mt][nt4][i] + bias);
            }
    }
}

// ---------------------------------------------------------------------------
// Edge kernel v13: ROW-MAJOR, zero global atomics.
// Evidence (R0-R4): two radically different schedules (persistent dbuf vs
// one-shot) land at 190 vs 189 µs with different occupancy — the time floor is
// invariant to scheduling. The invariant is ~11M device-scope f32 atomics
// (agg ~9.5M lane-ops + upd ~1.4M same-address) which must execute at the
// coherent memory-side path (per-XCD L2s are non-coherent). This version makes
// each block own RPB=29 rows (edges already counting-sorted by row), so agg
// and upd accumulate in LDS (ds-atomics) and are written ONCE with plain
// coalesced stores. Weight loads amortize over ~8 chunks.
__global__ __launch_bounds__(256, 3) void k_edge_rm(
    const short* __restrict__ H1,
    const int* __restrict__ rS, const int* __restrict__ cS,
    const float* __restrict__ pos,
    const float* __restrict__ w1c,
    const short* __restrict__ w2p, const float* __restrict__ b2,
    const short* __restrict__ c1p, const float* __restrict__ cb1,
    const float* __restrict__ cw2,
    const int* __restrict__ rowStart,
    float* __restrict__ agg, float* __restrict__ upd)
{
    __shared__ short t1[ET][136];
    __shared__ short mm[ET][136];
    __shared__ int   rIs[ET], cIs[ET];
    __shared__ float sred[ET];
    __shared__ float aggS[RPB][HID];
    __shared__ float updS[RPB][4];

    const int tid = threadIdx.x;
    const int l = tid & 63, w = tid >> 6;
    const int l16 = l & 15, quad = l >> 4;
    const int c0 = (2*w)*16 + l16, c1c = (2*w+1)*16 + l16;
    const int half = tid >> 7, ch = tid & 127;
    const int q = tid & 15;
    const int esub = tid >> 4;
    const int r0 = blockIdx.x * RPB;

    float wv[8];
    #pragma unroll
    for (int j = 0; j < 8; ++j) wv[j] = w1c[q*8 + j];

    s8 w2f[8], c1f[8];
    #pragma unroll
    for (int kc = 0; kc < 4; ++kc) {
        w2f[kc]     = *(const s8*)(w2p + (((size_t)(2*w)*4 + kc)*64 + l)*8);
        w2f[4 + kc] = *(const s8*)(w2p + (((size_t)(2*w+1)*4 + kc)*64 + l)*8);
        c1f[kc]     = *(const s8*)(c1p + (((size_t)(2*w)*4 + kc)*64 + l)*8);
        c1f[4 + kc] = *(const s8*)(c1p + (((size_t)(2*w+1)*4 + kc)*64 + l)*8);
    }
    const float bia2_0 = b2[c0],  bia2_1 = b2[c1c];
    const float biac_0 = cb1[c0], biac_1 = cb1[c1c];
    const float cw0    = cw2[c0], cw1v   = cw2[c1c];

    // zero LDS accumulators
    for (int j = tid; j < RPB*HID; j += 256) aggS[j >> 7][j & 127] = 0.f;
    if (tid < RPB) { updS[tid][0] = 0.f; updS[tid][1] = 0.f; updS[tid][2] = 0.f; }
    if (tid < ET) sred[tid] = 0.f;

    const int bstart = rowStart[r0];
    const int bend   = rowStart[r0 + RPB];
    __syncthreads();

    for (int eb = bstart; eb < bend; eb += ET) {
        // build chunk into t1 (tail edges masked to row r0, contribution 0)
        #pragma unroll
        for (int it = 0; it < 4; ++it) {
            int e = esub + 16*it;
            long idx = (long)eb + e;
            int r, c; float d2;
            if (idx < bend) {
                r = rS[idx]; c = cS[idx];
                float rx = pos[r*3+0] - pos[c*3+0];
                float ry = pos[r*3+1] - pos[c*3+1];
                float rz = pos[r*3+2] - pos[c*3+2];
                d2 = fminf(fmaxf(rx*rx + ry*ry + rz*rz, 1e-6f), 1e6f);
            } else { r = r0; c = r0; d2 = 0.f; }
            s8 va = *(const s8*)(H1 + (long)r*256 + q*8);
            s8 vb = *(const s8*)(H1 + (long)c*256 + 128 + q*8);
            s8 o;
            #pragma unroll
            for (int j = 0; j < 8; ++j)
                o[j] = f2b(siluf(b2f(va[j]) + b2f(vb[j]) + d2*wv[j]));
            *(s8*)&t1[e][q*8] = o;
            if (q == 0) { rIs[e] = r; cIs[e] = c; }
        }
        __syncthreads();                 // (1) t1 + meta ready

        // stage2 MFMA + mm epilogue
        {
            f4 acc[4][2];
            #pragma unroll
            for (int mt = 0; mt < 4; ++mt) { acc[mt][0] = (f4)0.f; acc[mt][1] = (f4)0.f; }
            #pragma unroll
            for (int it = 0; it < 4; ++it) {
                #pragma unroll
                for (int mt = 0; mt < 4; ++mt) {
                    s8 a = *(const s8*)&t1[mt*16 + l16][it*32 + quad*8];
                    acc[mt][0] = __builtin_amdgcn_mfma_f32_16x16x32_bf16(a, w2f[it],     acc[mt][0], 0, 0, 0);
                    acc[mt][1] = __builtin_amdgcn_mfma_f32_16x16x32_bf16(a, w2f[4 + it], acc[mt][1], 0, 0, 0);
                }
            }
            #pragma unroll
            for (int mt = 0; mt < 4; ++mt) {
                #pragma unroll
                for (int i = 0; i < 4; ++i) {
                    int row = mt*16 + quad*4 + i;
                    mm[row][c0]  = f2b(siluf(acc[mt][0][i] + bia2_0));
                    mm[row][c1c] = f2b(siluf(acc[mt][1][i] + bia2_1));
                }
            }
        }
        __syncthreads();                 // (2) mm ready

        // agg accumulation into LDS (run-length + ds-atomic; invalid edges add 0)
        {
            int e0 = half * 32;
            int cur = rIs[e0];
            float a = 0.f;
            #pragma unroll
            for (int e = e0; e < e0 + 32; ++e) {
                int r = rIs[e];
                if (r != cur) {
                    atomicAdd(&aggS[cur - r0][ch], a);
                    a = 0.f; cur = r;
                }
                float v = ((long)eb + e < bend) ? b2f(mm[e][ch]) : 0.f;
                a += v;
            }
            atomicAdd(&aggS[cur - r0][ch], a);
        }
        // stage3 MFMA -> sred
        {
            f4 acc3[4][2];
            #pragma unroll
            for (int mt = 0; mt < 4; ++mt) { acc3[mt][0] = (f4)0.f; acc3[mt][1] = (f4)0.f; }
            #pragma unroll
            for (int kc = 0; kc < 4; ++kc) {
                #pragma unroll
                for (int mt = 0; mt < 4; ++mt) {
                    s8 a = *(const s8*)&mm[mt*16 + l16][kc*32 + quad*8];
                    acc3[mt][0] = __builtin_amdgcn_mfma_f32_16x16x32_bf16(a, c1f[kc],     acc3[mt][0], 0, 0, 0);
                    acc3[mt][1] = __builtin_amdgcn_mfma_f32_16x16x32_bf16(a, c1f[4 + kc], acc3[mt][1], 0, 0, 0);
                }
            }
            #pragma unroll
            for (int mt = 0; mt < 4; ++mt) {
                #pragma unroll
                for (int i = 0; i < 4; ++i) {
                    float p = siluf(acc3[mt][0][i] + biac_0) * cw0
                            + siluf(acc3[mt][1][i] + biac_1) * cw1v;
                    p += __shfl_xor(p, 1);
                    p += __shfl_xor(p, 2);
                    p += __shfl_xor(p, 4);
                    p += __shfl_xor(p, 8);
                    if (l16 == 0) {
                        int row = mt*16 + quad*4 + i;
                        atomicAdd(&sred[row], p);
                    }
                }
            }
        }
        // upd operands pre-read before barrier (3)
        int   ur = r0;
        float urx = 0.f, ury = 0.f, urz = 0.f;
        bool  uvalid = false;
        if (tid < ET) {
            uvalid = ((long)eb + tid < bend);
            if (uvalid) {
                ur = rIs[tid];
                int uc = cIs[tid];
                urx = pos[ur*3+0] - pos[uc*3+0];
                ury = pos[ur*3+1] - pos[uc*3+1];
                urz = pos[ur*3+2] - pos[uc*3+2];
            }
        }
        __syncthreads();                 // (3) sred complete, mm consumed

        if (tid < ET) {
            if (uvalid) {
                float cwv = fminf(fmaxf(sred[tid], -1.f), 1.f);
                atomicAdd(&updS[ur - r0][0], cwv*urx);
                atomicAdd(&updS[ur - r0][1], cwv*ury);
                atomicAdd(&updS[ur - r0][2], cwv*urz);
            }
            sred[tid] = 0.f;
        }
        // no barrier needed here: next build overwrites t1/rIs, which nothing
        // after (3) reads; sred reset completes before its next use (after (2)).
    }
    __syncthreads();                     // all LDS accumulation complete

    // single coalesced writeout — the only global writes of this kernel
    for (int j = tid; j < RPB*HID; j += 256)
        agg[(long)r0*HID + j] = aggS[j >> 7][j & 127];
    if (tid < RPB*3) {
        int i = tid / 3, d = tid - i*3;
        upd[(r0 + i)*3 + d] = updS[i][d];
    }
}

// ---------------------------------------------------------------------------
// Node kernel + fused H1(next layer) or fused head (last layer).
__global__ __launch_bounds__(256) void k_node_mfma(
    short* __restrict__ hb, float* __restrict__ agg,
    const float* __restrict__ w1p_dummy, const float* __restrict__ b1n,
    const short* __restrict__ w2p, const float* __restrict__ b2n,
    const float* __restrict__ lg, const float* __restrict__ lb,
    float* __restrict__ pos, float* __restrict__ upd,
    const int* __restrict__ rowStart,
    const short* __restrict__ wcatn, const float* __restrict__ b1next,
    short* __restrict__ H1,
    const short* __restrict__ w1p, const short* __restrict__ hw1p,
    const float* __restrict__ hb1,
    const float* __restrict__ hw2, const float* __restrict__ hb2,
    void* __restrict__ out, const int* __restrict__ flags)
{
    __shared__ short x[64][264];
    __shared__ short t1[64][144];
    __shared__ float mus[64], rstds[64];
    __shared__ float posS[64][3];
    float (*hn)[132] = (float (*)[132])&x[0][0];
    float (*hid)[68] = (float (*)[68])&x[0][0];
    (void)w1p_dummy;

    const int tid = threadIdx.x;
    const int n0 = blockIdx.x * 64;

    #pragma unroll
    for (int it = 0; it < 4; ++it) {
        int idx = it*256 + tid;
        int e = idx >> 4, qq = idx & 15;
        *(int4*)&x[e][qq*8] = *(const int4*)(hb + (long)(n0+e)*HID + qq*8);
    }
    #pragma unroll
    for (int it = 0; it < 8; ++it) {
        int idx = it*256 + tid;
        int e = idx >> 5, qq = idx & 31;
        float4 v = *(const float4*)(agg + (long)(n0+e)*HID + qq*4);
        short4 sv;
        sv.x = f2b(v.x); sv.y = f2b(v.y); sv.z = f2b(v.z); sv.w = f2b(v.w);
        *(short4*)&x[e][128 + qq*4] = sv;
    }
    __syncthreads();

    const int l = tid & 63, w = tid >> 6;
    const int l16 = l & 15, quad = l >> 4;
    const int nt0 = 2*w, nt1 = 2*w + 1;
    const int c0 = nt0*16 + l16, c1c = nt1*16 + l16;

    {
        f4 acc[4][2];
        #pragma unroll
        for (int mt = 0; mt < 4; ++mt) { acc[mt][0] = (f4)0.f; acc[mt][1] = (f4)0.f; }
        #pragma unroll
        for (int kc = 0; kc < 8; ++kc) {
            s8 b0  = *(const s8*)(w1p + (((size_t)nt0*8 + kc)*64 + l)*8);
            s8 b1f = *(const s8*)(w1p + (((size_t)nt1*8 + kc)*64 + l)*8);
            #pragma unroll
            for (int mt = 0; mt < 4; ++mt) {
                s8 a = *(const s8*)&x[mt*16 + l16][kc*32 + quad*8];
                acc[mt][0] = __builtin_amdgcn_mfma_f32_16x16x32_bf16(a, b0,  acc[mt][0], 0, 0, 0);
                acc[mt][1] = __builtin_amdgcn_mfma_f32_16x16x32_bf16(a, b1f, acc[mt][1], 0, 0, 0);
            }
        }
        float bia0 = b1n[c0], bia1 = b1n[c1c];
        #pragma unroll
        for (int mt = 0; mt < 4; ++mt) {
            #pragma unroll
            for (int i = 0; i < 4; ++i) {
                int row = mt*16 + quad*4 + i;
                t1[row][c0]  = f2b(siluf(acc[mt][0][i] + bia0));
                t1[row][c1c] = f2b(siluf(acc[mt][1][i] + bia1));
            }
        }
    }
    __syncthreads();

    {
        f4 acc[4][2];
        #pragma unroll
        for (int mt = 0; mt < 4; ++mt) { acc[mt][0] = (f4)0.f; acc[mt][1] = (f4)0.f; }
        #pragma unroll
        for (int kc = 0; kc < 4; ++kc) {
            s8 b0  = *(const s8*)(w2p + (((size_t)nt0*4 + kc)*64 + l)*8);
            s8 b1f = *(const s8*)(w2p + (((size_t)nt1*4 + kc)*64 + l)*8);
            #pragma unroll
            for (int mt = 0; mt < 4; ++mt) {
                s8 a = *(const s8*)&t1[mt*16 + l16][kc*32 + quad*8];
                acc[mt][0] = __builtin_amdgcn_mfma_f32_16x16x32_bf16(a, b0,  acc[mt][0], 0, 0, 0);
                acc[mt][1] = __builtin_amdgcn_mfma_f32_16x16x32_bf16(a, b1f, acc[mt][1], 0, 0, 0);
            }
        }
        float bia0 = b2n[c0], bia1 = b2n[c1c];
        __syncthreads();
        #pragma unroll
        for (int mt = 0; mt < 4; ++mt) {
            #pragma unroll
            for (int i = 0; i < 4; ++i) {
                int row = mt*16 + quad*4 + i;
                hn[row][c0]  = acc[mt][0][i] + bia0;
                hn[row][c1c] = acc[mt][1][i] + bia1;
            }
        }
    }
    __syncthreads();

    {
        int r = tid >> 2, part = tid & 3;
        float s = 0.f, qv = 0.f;
        #pragma unroll
        for (int j = 0; j < 32; ++j) {
            float v = hn[r][part + 4*j];
            s += v; qv += v*v;
        }
        s += __shfl_xor(s, 1); qv += __shfl_xor(qv, 1);
        s += __shfl_xor(s, 2); qv += __shfl_xor(qv, 2);
        if (part == 0) {
            float mu = s * (1.0f/HID);
            float var = qv * (1.0f/HID) - mu*mu;
            mus[r] = mu;
            rstds[r] = rsqrtf(var + 1e-5f);
        }
    }
    __syncthreads();

    #pragma unroll
    for (int it = 0; it < 32; ++it) {
        int idx = it*256 + tid;
        int r = idx >> 7, c = idx & 127;
        float v = (hn[r][c] - mus[r]) * rstds[r] * lg[c] + lb[c];
        short s = f2b(v);
        hb[(long)(n0 + r)*HID + c] = s;
        t1[r][c] = s;
    }
    if (tid < 192) {
        int i = tid / 3, d = tid - i*3;
        int n = n0 + i;
        float dg = (float)(rowStart[n+1] - rowStart[n]);
        float np = pos[n*3+d] + upd[n*3+d] / (dg + 1e-6f);
        pos[n*3+d] = np;
        posS[i][d] = np;
    }
    __syncthreads();

    if (wcatn) {
        f4 acc[4][4];
        #pragma unroll
        for (int mt = 0; mt < 4; ++mt)
            #pragma unroll
            for (int nt4 = 0; nt4 < 4; ++nt4) acc[mt][nt4] = (f4)0.f;
        #pragma unroll
        for (int kc = 0; kc < 4; ++kc) {
            s8 a[4];
            #pragma unroll
            for (int mt = 0; mt < 4; ++mt)
                a[mt] = *(const s8*)&t1[mt*16 + l16][kc*32 + quad*8];
            #pragma unroll
            for (int nt4 = 0; nt4 < 4; ++nt4) {
                int nt = w*4 + nt4;
                s8 b = *(const s8*)(wcatn + (((size_t)nt*4 + kc)*64 + l)*8);
                #pragma unroll
                for (int mt = 0; mt < 4; ++mt)
                    acc[mt][nt4] = __builtin_amdgcn_mfma_f32_16x16x32_bf16(a[mt], b, acc[mt][nt4], 0, 0, 0);
            }
        }
        #pragma unroll
        for (int nt4 = 0; nt4 < 4; ++nt4) {
            int col = (w*4 + nt4)*16 + l16;
            float bias = (col < 128) ? b1next[col] : 0.f;
            #pragma unroll
            for (int mt = 0; mt < 4; ++mt)
                #pragma unroll
                for (int i = 0; i < 4; ++i) {
                    int row = mt*16 + quad*4 + i;
                    H1[(long)(n0 + row)*256 + col] = f2b(acc[mt][nt4][i] + bias);
                }
        }
    } else {
        f4 acc[4];
        #pragma unroll
        for (int mt = 0; mt < 4; ++mt) acc[mt] = (f4)0.f;
        #pragma unroll
        for (int kc = 0; kc < 4; ++kc) {
            s8 b = *(const s8*)(hw1p + (((size_t)w*4 + kc)*64 + l)*8);
            #pragma unroll
            for (int mt = 0; mt < 4; ++mt) {
                s8 a = *(const s8*)&t1[mt*16 + l16][kc*32 + quad*8];
                acc[mt] = __builtin_amdgcn_mfma_f32_16x16x32_bf16(a, b, acc[mt], 0, 0, 0);
            }
        }
        int col = w*16 + l16;
        float bias = hb1[col];
        #pragma unroll
        for (int mt = 0; mt < 4; ++mt)
            #pragma unroll
            for (int i = 0; i < 4; ++i) {
                int row = mt*16 + quad*4 + i;
                hid[row][col] = siluf(acc[mt][i] + bias);
            }
        __syncthreads();
        if (tid < 192) {
            int r = tid / 3, cc = tid - r*3;
            float a2 = hb2[cc];
            #pragma unroll
            for (int k = 0; k < 64; ++k) a2 += hid[r][k] * hw2[k*3 + cc];
            int n = n0 + r;
            float v = posS[r][cc] + a2;
            if (flags[0]) ((__hip_bfloat16*)out)[n*3+cc] = __float2bfloat16(v);
            else          ((float*)out)[n*3+cc] = v;
        }
    }
}

// ---------------------------------------------------------------------------
extern "C" void kernel_launch(void* const* d_in, const int* in_sizes, int n_in,
                              void* d_out, int out_size, void* d_ws, size_t ws_size,
                              hipStream_t stream)
{
    (void)in_sizes; (void)n_in; (void)out_size; (void)ws_size;

    int* flags = (int*)d_ws;
    float* base = (float*)d_ws;
    size_t off = 64;
    auto alloc = [&](size_t n) { float* p = base + off; off += (n + 63) & ~63ull; return p; };

    static const int aidx[24] = {0,1,3,4,5,6,7,8,9,10,11,12,13,14,15,16,17,18,19,20,21,22,23,24};
    static const int alen[24] = {
        BB*LAT, NN*AF, NA*3, LAT*HID, HID, AF*HID, HID,
        NL*257*HID, NL*HID, NL*HID*HID, NL*HID,
        NL*256*HID, NL*HID, NL*HID*HID, NL*HID,
        NL*HID*HID, NL*HID, NL*HID, NL*HID, NL*HID,
        HID*64, 64, 64*3, 3
    };
    CvtDesc cd;
    float* fp[24];
    for (int a = 0; a < 24; ++a) {
        fp[a] = alloc((size_t)alen[a]);
        cd.src[a] = d_in[aidx[a]];
        cd.dst[a] = fp[a];
        cd.len[a] = alen[a];
    }
    float* agg = alloc((size_t)NN*HID);
    float* pos = alloc((size_t)NN*3);
    float* upd = alloc((size_t)NN*3);
    short* hb  = (short*)alloc((size_t)NN*HID/2);
    short* H1  = (short*)alloc((size_t)NN*256/2);
    short* wcatp = (short*)alloc((size_t)NL*32768/2);
    short* w2p = (short*)alloc((size_t)NL*16384/2);
    short* c1p = (short*)alloc((size_t)NL*16384/2);
    short* nw1p = (short*)alloc((size_t)NL*32768/2);
    short* nw2p = (short*)alloc((size_t)NL*16384/2);
    short* hw1p = (short*)alloc((size_t)8192/2);
    int* cnt      = (int*)alloc((size_t)NN);
    int* rowStart = (int*)alloc((size_t)NN + 1);
    int* cursor   = (int*)alloc((size_t)NN);
    int* rS       = (int*)alloc((size_t)NE);
    int* cS       = (int*)alloc((size_t)NE);
    const int* eidx = (const int*)d_in[2];

    k_detect<<<1, 256, 0, stream>>>((const unsigned short*)d_in[0],
                                    (const unsigned int*)d_in[2], flags);
    k_convert<<<dim3((NN*AF + 255)/256, 24), 256, 0, stream>>>(cd, flags);

    PackJobs pj;
    for (int l = 0; l < NL; ++l) {
        int b5 = l*5;
        pj.src[b5+0] = fp[7]  + (size_t)l*257*HID; pj.dst[b5+0] = wcatp + (size_t)l*32768; pj.K[b5+0] = 256; pj.mode[b5+0] = 1;
        pj.src[b5+1] = fp[9]  + (size_t)l*HID*HID; pj.dst[b5+1] = w2p   + (size_t)l*16384; pj.K[b5+1] = 128; pj.mode[b5+1] = 0;
        pj.src[b5+2] = fp[15] + (size_t)l*HID*HID; pj.dst[b5+2] = c1p   + (size_t)l*16384; pj.K[b5+2] = 128; pj.mode[b5+2] = 0;
        pj.src[b5+3] = fp[11] + (size_t)l*256*HID; pj.dst[b5+3] = nw1p  + (size_t)l*32768; pj.K[b5+3] = 256; pj.mode[b5+3] = 0;
        pj.src[b5+4] = fp[13] + (size_t)l*HID*HID; pj.dst[b5+4] = nw2p  + (size_t)l*16384; pj.K[b5+4] = 128; pj.mode[b5+4] = 0;
    }
    pj.src[10] = fp[20]; pj.dst[10] = hw1p; pj.K[10] = 128; pj.mode[10] = 2;
    k_packall<<<dim3(128, 11), 256, 0, stream>>>(pj);

    // counting sort edges by row
    hipMemsetAsync(cnt, 0, (size_t)NN*sizeof(int), stream);
    k_hist<<<(NE + 255)/256, 256, 0, stream>>>(eidx, flags, cnt);
    k_scan<<<1, 1024, 0, stream>>>(cnt, rowStart, cursor);
    k_scatter<<<(NE + 255)/256, 256, 0, stream>>>(eidx, flags, cursor, rS, cS);

    k_init3<<<NN/64, 256, 0, stream>>>(fp[0], fp[3], fp[4],
                                       fp[1], fp[5], fp[6], fp[2], pos, hb,
                                       wcatp, fp[8], H1, agg, upd);

    for (int l = 0; l < NL; ++l) {
        k_edge_rm<<<NBLK, 256, 0, stream>>>(H1, rS, cS, pos,
            fp[7] + (size_t)l*257*HID + 256*HID,       // w1c (d2 row, f32)
            w2p + (size_t)l*16384, fp[10] + (size_t)l*HID,
            c1p + (size_t)l*16384, fp[16] + (size_t)l*HID,
            fp[17] + (size_t)l*HID,
            rowStart, agg, upd);
        const short* wcatn = (l+1 < NL) ? (wcatp + (size_t)(l+1)*32768) : nullptr;
        const float* b1nx  = (l+1 < NL) ? (fp[8] + (size_t)(l+1)*HID) : fp[8];
        k_node_mfma<<<NN/64, 256, 0, stream>>>(hb, agg,
            nullptr, fp[12] + (size_t)l*HID,
            nw2p + (size_t)l*16384, fp[14] + (size_t)l*HID,
            fp[18] + (size_t)l*HID, fp[19] + (size_t)l*HID,
            pos, upd, rowStart, wcatn, b1nx, H1,
            nw1p + (size_t)l*32768, hw1p, fp[21], fp[22], fp[23], d_out, flags);
    }
}

// Round 6
// 649.268 us; speedup vs baseline: 1.4830x; 1.4830x over previous
//
#include <hip/hip_runtime.h>
#include <hip/hip_bf16.h>

#define BB 512
#define NA 58
#define LAT 64
#define HID 128
#define AF 10
#define NL 2
#define NN (BB*NA)      // 29696
#define NE (NN*16)      // 475136
#define ET 64           // edges per tile
#define NTILE (NE/ET)   // 7424

typedef __attribute__((ext_vector_type(8))) short s8;
typedef __attribute__((ext_vector_type(4))) float f4;

struct CvtDesc {
    const void* src[24];
    float*      dst[24];
    int         len[24];
};

struct PackJobs {
    const float* src[11];
    short*       dst[11];
    int          K[11];
    int          mode[11];   // 0: [K][128] B-frag; 1: edge-w1 concat; 2: [K][64] B-frag
};

__device__ __forceinline__ float siluf(float x) {
    return x * __builtin_amdgcn_rcpf(1.0f + __expf(-x));
}

__device__ __forceinline__ short f2b(float x) {
    __hip_bfloat16 b = __float2bfloat16(x);
    return *(short*)&b;
}

__device__ __forceinline__ float b2f(short s) {
    return __uint_as_float(((unsigned int)(unsigned short)s) << 16);
}

// ---------------------------------------------------------------------------
__global__ void k_detect(const unsigned short* __restrict__ z16,
                         const unsigned int* __restrict__ e32,
                         int* __restrict__ flags) {
    __shared__ int sbf, si64;
    if (threadIdx.x == 0) { sbf = 0; si64 = 0; }
    __syncthreads();
    int c1 = 0, c2 = 0;
    for (int i = threadIdx.x; i < 1024; i += 256) {
        unsigned short v = z16[2*i];
        int e = (v >> 7) & 0xFF;
        if (e >= 100 && e <= 140) c1++;
        if (e32[2*i + 1] == 0u) c2++;
    }
    atomicAdd(&sbf, c1);
    atomicAdd(&si64, c2);
    __syncthreads();
    if (threadIdx.x == 0) {
        flags[0] = (sbf  > 600) ? 1 : 0;
        flags[1] = (si64 > 600) ? 1 : 0;
    }
}

__global__ void k_convert(CvtDesc d, const int* __restrict__ flags) {
    int a = blockIdx.y;
    int i = blockIdx.x * blockDim.x + threadIdx.x;
    int n = d.len[a];
    if (i >= n) return;
    if (flags[0]) {
        d.dst[a][i] = __bfloat162float(((const __hip_bfloat16*)d.src[a])[i]);
    } else {
        d.dst[a][i] = ((const float*)d.src[a])[i];
    }
}

__global__ void k_packall(PackJobs pj) {
    int j = blockIdx.y;
    int idx = blockIdx.x * 256 + threadIdx.x;
    const float* w = pj.src[j];
    short* o = pj.dst[j];
    int mode = pj.mode[j];
    if (mode == 0) {
        int K = pj.K[j];
        if (idx >= 128*K) return;
        int jj = idx & 7;
        int l  = (idx >> 3) & 63;
        int rest = idx >> 9;
        int KC = K >> 5;
        int kc = rest % KC;
        int nt = rest / KC;
        int n = nt*16 + (l & 15);
        int k = kc*32 + (l >> 4)*8 + jj;
        o[idx] = f2b(w[k*128 + n]);
    } else if (mode == 1) {
        if (idx >= 32768) return;
        int jj = idx & 7;
        int l  = (idx >> 3) & 63;
        int rest = idx >> 9;
        int kc = rest & 3;
        int nt = rest >> 2;
        int n = nt*16 + (l & 15);
        int k = kc*32 + (l >> 4)*8 + jj;
        float v = (n < 128) ? w[k*128 + n] : w[(128 + k)*128 + (n - 128)];
        o[idx] = f2b(v);
    } else {
        if (idx >= 8192) return;
        int jj = idx & 7;
        int l  = (idx >> 3) & 63;
        int rest = idx >> 9;
        int kc = rest & 3;
        int nt = rest >> 2;
        int n = nt*16 + (l & 15);
        int k = kc*32 + (l >> 4)*8 + jj;
        o[idx] = f2b(w[k*64 + n]);
    }
}

// ---------------------------------------------------------------------------
__global__ void k_hist(const int* __restrict__ eidx, const int* __restrict__ flags,
                       int* __restrict__ cnt) {
    int e = blockIdx.x * 256 + threadIdx.x;
    if (e >= NE) return;
    int is64 = flags[1];
    int r = eidx[is64 ? 2*(long)e : (long)e];
    atomicAdd(&cnt[r], 1);
}

__global__ __launch_bounds__(1024) void k_scan(const int* __restrict__ cnt,
                                               int* __restrict__ rowStart,
                                               int* __restrict__ cursor) {
    __shared__ int part[1024];
    int t = threadIdx.x;
    int base = t * 29;                    // NN == 1024*29
    int loc[29];
    int s = 0;
    #pragma unroll
    for (int i = 0; i < 29; ++i) { loc[i] = s; s += cnt[base + i]; }
    part[t] = s;
    __syncthreads();
    for (int d = 1; d < 1024; d <<= 1) {
        int v = (t >= d) ? part[t - d] : 0;
        __syncthreads();
        part[t] += v;
        __syncthreads();
    }
    int pre = (t == 0) ? 0 : part[t - 1];
    #pragma unroll
    for (int i = 0; i < 29; ++i) {
        int v = pre + loc[i];
        rowStart[base + i] = v;
        cursor[base + i] = v;
    }
    if (t == 1023) rowStart[NN] = pre + s;
}

__global__ void k_scatter(const int* __restrict__ eidx, const int* __restrict__ flags,
                          int* __restrict__ cursor,
                          int* __restrict__ rS, int* __restrict__ cS) {
    int e = blockIdx.x * 256 + threadIdx.x;
    if (e >= NE) return;
    int is64 = flags[1];
    long ge = e, gc = (long)e + NE;
    int r = eidx[is64 ? 2*ge : ge];
    int c = eidx[is64 ? 2*gc : gc];
    int p = atomicAdd(&cursor[r], 1);
    rS[p] = r; cS[p] = c;
}

// ---------------------------------------------------------------------------
// init3: fused hz GEMV + h init (bf16) + pos init + zero agg/upd + H1(l0) GEMM.
__global__ __launch_bounds__(256) void k_init3(
    const float* __restrict__ z, const float* __restrict__ lw,
    const float* __restrict__ lbz,
    const float* __restrict__ at,
    const float* __restrict__ aw, const float* __restrict__ ab,
    const float* __restrict__ ic,
    float* __restrict__ pos, short* __restrict__ hb,
    const short* __restrict__ wcat0, const float* __restrict__ b10,
    short* __restrict__ H1, float* __restrict__ agg, float* __restrict__ upd)
{
    __shared__ short x[64][136];
    __shared__ float awS[AF][HID];
    __shared__ float atS[64][AF+2];
    __shared__ float zbS[3][LAT];
    __shared__ float hzS[3][HID];
    const int tid = threadIdx.x;
    const int n0 = blockIdx.x * 64;
    const int b0 = n0 / NA;
    const int nb = (n0 + 63) / NA - b0 + 1;   // 1..3

    for (int i = tid; i < AF*HID; i += 256) awS[i/HID][i%HID] = aw[i];
    for (int i = tid; i < 64*AF; i += 256)
        atS[i/AF][i%AF] = at[(long)(n0 + i/AF)*AF + i%AF];
    for (int i = tid; i < nb*LAT; i += 256) {
        int bi = i / LAT, k = i - bi*LAT;
        int bidx = b0 + bi;
        zbS[bi][k] = (bidx < BB) ? z[bidx*LAT + k] : 0.f;
    }
    __syncthreads();

    for (int i = tid; i < nb*HID; i += 256) {
        int bi = i / HID, c = i - bi*HID;
        float acc = lbz[c];
        #pragma unroll
        for (int k = 0; k < LAT; ++k) acc += zbS[bi][k] * lw[k*HID + c];
        hzS[bi][c] = acc;
    }
    __syncthreads();

    #pragma unroll
    for (int it = 0; it < 32; ++it) {
        int idx = it*256 + tid;
        int r = idx >> 7, c = idx & 127;
        int n = n0 + r;
        float v = hzS[n/NA - b0][c] + ab[c];
        #pragma unroll
        for (int f = 0; f < AF; ++f) v += atS[r][f]*awS[f][c];
        short s = f2b(v);
        x[r][c] = s;
        hb[(long)n*HID + c] = s;
    }
    if (tid < 192) {
        int i = tid/3, d = tid - i*3;
        int n = n0 + i;
        pos[n*3 + d] = ic[(n % NA)*3 + d];
        upd[n*3 + d] = 0.f;
    }
    {
        f4* a4 = (f4*)(agg + (long)n0*HID);
        for (int j = tid; j < 64*HID/4; j += 256) a4[j] = (f4)0.f;
    }
    __syncthreads();

    const int l = tid & 63, w = tid >> 6;
    const int l16 = l & 15, quad = l >> 4;
    f4 acc[4][4];
    #pragma unroll
    for (int mt = 0; mt < 4; ++mt)
        #pragma unroll
        for (int nt4 = 0; nt4 < 4; ++nt4) acc[mt][nt4] = (f4)0.f;
    #pragma unroll
    for (int kc = 0; kc < 4; ++kc) {
        s8 a[4];
        #pragma unroll
        for (int mt = 0; mt < 4; ++mt)
            a[mt] = *(const s8*)&x[mt*16 + l16][kc*32 + quad*8];
        #pragma unroll
        for (int nt4 = 0; nt4 < 4; ++nt4) {
            int nt = w*4 + nt4;
            s8 b = *(const s8*)(wcat0 + (((size_t)nt*4 + kc)*64 + l)*8);
            #pragma unroll
            for (int mt = 0; mt < 4; ++mt)
                acc[mt][nt4] = __builtin_amdgcn_mfma_f32_16x16x32_bf16(a[mt], b, acc[mt][nt4], 0, 0, 0);
        }
    }
    #pragma unroll
    for (int nt4 = 0; nt4 < 4; ++nt4) {
        int col = (w*4 + nt4)*16 + l16;
        float bias = (col < 128) ? b10[col] : 0.f;
        #pragma unroll
        for (int mt = 0; mt < 4; ++mt)
            #pragma unroll
            for (int i = 0; i < 4; ++i) {
                int row = mt*16 + quad*4 + i;
                H1[(long)(n0 + row)*256 + col] = f2b(acc[mt][nt4][i] + bias);
            }
    }
}

// ---------------------------------------------------------------------------
// Edge kernel v14: one-shot (R4 structure, best-known 189 µs) + mm ALIASED
// onto t1 => LDS 35.8K -> 18.2K => up to 8 blocks/CU (R4 measured VGPR=60,
// so 8 waves/SIMD fit the register file). One extra barrier vs R4; unlike
// R2's persistent version, one-shot blocks have no buffer rotation to
// serialize, and the doubled block-level concurrency is the one scheduling
// lever never tested in this regime. launch_bounds min-waves=6 caps VGPR at
// 84 (where every prior variant naturally landed) — avoids R1's spill cliff.
__global__ __launch_bounds__(256, 6) void k_edge_os(
    const short* __restrict__ H1,
    const int* __restrict__ rS, const int* __restrict__ cS,
    const float* __restrict__ pos,
    const float* __restrict__ w1c,
    const short* __restrict__ w2p, const float* __restrict__ b2,
    const short* __restrict__ c1p, const float* __restrict__ cb1,
    const float* __restrict__ cw2,
    float* __restrict__ agg, float* __restrict__ upd)
{
    __shared__ short t1[ET][136];        // doubles as mm after barrier (A2)
    __shared__ int   rIs[ET], cIs[ET];
    __shared__ float sred[ET];

    const int tid = threadIdx.x;
    const int l = tid & 63, w = tid >> 6;
    const int l16 = l & 15, quad = l >> 4;
    const int c0 = (2*w)*16 + l16, c1c = (2*w+1)*16 + l16;
    const int half = tid >> 7, ch = tid & 127;
    const int q = tid & 15;
    const int esub = tid >> 4;
    const int T = blockIdx.x;

    float wv[8];
    #pragma unroll
    for (int j = 0; j < 8; ++j) wv[j] = w1c[q*8 + j];

    s8 w2f[8], c1f[8];
    #pragma unroll
    for (int kc = 0; kc < 4; ++kc) {
        w2f[kc]     = *(const s8*)(w2p + (((size_t)(2*w)*4 + kc)*64 + l)*8);
        w2f[4 + kc] = *(const s8*)(w2p + (((size_t)(2*w+1)*4 + kc)*64 + l)*8);
        c1f[kc]     = *(const s8*)(c1p + (((size_t)(2*w)*4 + kc)*64 + l)*8);
        c1f[4 + kc] = *(const s8*)(c1p + (((size_t)(2*w+1)*4 + kc)*64 + l)*8);
    }
    const float bia2_0 = b2[c0],  bia2_1 = b2[c1c];
    const float biac_0 = cb1[c0], biac_1 = cb1[c1c];
    const float cw0    = cw2[c0], cw1v   = cw2[c1c];

    // PREIDX + build t1 for this block's single tile
    const long eb = (long)T * ET;
    if (tid < ET) sred[tid] = 0.f;
    #pragma unroll
    for (int it = 0; it < 4; ++it) {
        int e = esub + 16*it;
        int r = rS[eb + e], c = cS[eb + e];
        float rx = pos[r*3+0] - pos[c*3+0];
        float ry = pos[r*3+1] - pos[c*3+1];
        float rz = pos[r*3+2] - pos[c*3+2];
        float d2 = fminf(fmaxf(rx*rx + ry*ry + rz*rz, 1e-6f), 1e6f);
        s8 va = *(const s8*)(H1 + (long)r*256 + q*8);
        s8 vb = *(const s8*)(H1 + (long)c*256 + 128 + q*8);
        s8 o;
        #pragma unroll
        for (int j = 0; j < 8; ++j)
            o[j] = f2b(siluf(b2f(va[j]) + b2f(vb[j]) + d2*wv[j]));
        *(s8*)&t1[e][q*8] = o;
        if (q == 0) { rIs[e] = r; cIs[e] = c; }
    }
    __syncthreads();                     // (A) t1 + meta ready

    // stage2 MFMA (reads all of t1)
    f4 acc[4][2];
    #pragma unroll
    for (int mt = 0; mt < 4; ++mt) { acc[mt][0] = (f4)0.f; acc[mt][1] = (f4)0.f; }
    #pragma unroll
    for (int it = 0; it < 4; ++it) {
        #pragma unroll
        for (int mt = 0; mt < 4; ++mt) {
            s8 a = *(const s8*)&t1[mt*16 + l16][it*32 + quad*8];
            acc[mt][0] = __builtin_amdgcn_mfma_f32_16x16x32_bf16(a, w2f[it],     acc[mt][0], 0, 0, 0);
            acc[mt][1] = __builtin_amdgcn_mfma_f32_16x16x32_bf16(a, w2f[4 + it], acc[mt][1], 0, 0, 0);
        }
    }
    __syncthreads();                     // (A2) all t1 reads done — safe to overwrite

    // mm epilogue written into t1's space
    short (*mm)[136] = t1;
    #pragma unroll
    for (int mt = 0; mt < 4; ++mt) {
        #pragma unroll
        for (int i = 0; i < 4; ++i) {
            int row = mt*16 + quad*4 + i;
            mm[row][c0]  = f2b(siluf(acc[mt][0][i] + bia2_0));
            mm[row][c1c] = f2b(siluf(acc[mt][1][i] + bia2_1));
        }
    }
    __syncthreads();                     // (B) mm ready

    // agg: run-length dedup over sorted rows, atomics drain under stage3
    {
        int e0 = half * 32;
        int cur = rIs[e0];
        float a = 0.f;
        #pragma unroll
        for (int e = e0; e < e0 + 32; ++e) {
            int r = rIs[e];
            if (r != cur) {
                atomicAdd(&agg[(long)cur*HID + ch], a);
                a = 0.f; cur = r;
            }
            a += b2f(mm[e][ch]);
        }
        atomicAdd(&agg[(long)cur*HID + ch], a);
    }
    // stage3
    {
        f4 acc3[4][2];
        #pragma unroll
        for (int mt = 0; mt < 4; ++mt) { acc3[mt][0] = (f4)0.f; acc3[mt][1] = (f4)0.f; }
        #pragma unroll
        for (int kc = 0; kc < 4; ++kc) {
            #pragma unroll
            for (int mt = 0; mt < 4; ++mt) {
                s8 a = *(const s8*)&mm[mt*16 + l16][kc*32 + quad*8];
                acc3[mt][0] = __builtin_amdgcn_mfma_f32_16x16x32_bf16(a, c1f[kc],     acc3[mt][0], 0, 0, 0);
                acc3[mt][1] = __builtin_amdgcn_mfma_f32_16x16x32_bf16(a, c1f[4 + kc], acc3[mt][1], 0, 0, 0);
            }
        }
        #pragma unroll
        for (int mt = 0; mt < 4; ++mt) {
            #pragma unroll
            for (int i = 0; i < 4; ++i) {
                float p = siluf(acc3[mt][0][i] + biac_0) * cw0
                        + siluf(acc3[mt][1][i] + biac_1) * cw1v;
                p += __shfl_xor(p, 1);
                p += __shfl_xor(p, 2);
                p += __shfl_xor(p, 4);
                p += __shfl_xor(p, 8);
                if (l16 == 0) {
                    int row = mt*16 + quad*4 + i;
                    atomicAdd(&sred[row], p);
                }
            }
        }
    }
    // upd operands (rIs/cIs stable — single tile)
    int   ur = 0;
    float urx = 0.f, ury = 0.f, urz = 0.f;
    if (tid < ET) {
        ur = rIs[tid];
        int uc = cIs[tid];
        urx = pos[ur*3+0] - pos[uc*3+0];
        ury = pos[ur*3+1] - pos[uc*3+1];
        urz = pos[ur*3+2] - pos[uc*3+2];
    }
    __syncthreads();                     // (C) sred complete

    if (tid < ET) {
        float cwv = fminf(fmaxf(sred[tid], -1.f), 1.f);
        atomicAdd(&upd[ur*3+0], cwv*urx);
        atomicAdd(&upd[ur*3+1], cwv*ury);
        atomicAdd(&upd[ur*3+2], cwv*urz);
    }
}

// ---------------------------------------------------------------------------
// Node kernel + fused H1(next layer) or fused head (last layer).
__global__ __launch_bounds__(256) void k_node_mfma(
    short* __restrict__ hb, float* __restrict__ agg,
    const short* __restrict__ w1p, const float* __restrict__ b1n,
    const short* __restrict__ w2p, const float* __restrict__ b2n,
    const float* __restrict__ lg, const float* __restrict__ lb,
    float* __restrict__ pos, float* __restrict__ upd,
    const int* __restrict__ rowStart,
    const short* __restrict__ wcatn, const float* __restrict__ b1next,
    short* __restrict__ H1,
    const short* __restrict__ hw1p, const float* __restrict__ hb1,
    const float* __restrict__ hw2, const float* __restrict__ hb2,
    void* __restrict__ out, const int* __restrict__ flags)
{
    __shared__ short x[64][264];
    __shared__ short t1[64][144];
    __shared__ float mus[64], rstds[64];
    __shared__ float posS[64][3];
    float (*hn)[132] = (float (*)[132])&x[0][0];
    float (*hid)[68] = (float (*)[68])&x[0][0];

    const int tid = threadIdx.x;
    const int n0 = blockIdx.x * 64;

    #pragma unroll
    for (int it = 0; it < 4; ++it) {
        int idx = it*256 + tid;
        int e = idx >> 4, qq = idx & 15;
        *(int4*)&x[e][qq*8] = *(const int4*)(hb + (long)(n0+e)*HID + qq*8);
    }
    #pragma unroll
    for (int it = 0; it < 8; ++it) {
        int idx = it*256 + tid;
        int e = idx >> 5, qq = idx & 31;
        float4 v = *(const float4*)(agg + (long)(n0+e)*HID + qq*4);
        short4 sv;
        sv.x = f2b(v.x); sv.y = f2b(v.y); sv.z = f2b(v.z); sv.w = f2b(v.w);
        *(short4*)&x[e][128 + qq*4] = sv;
    }
    __syncthreads();

    {
        f4* a4 = (f4*)(agg + (long)n0*HID);
        for (int j = tid; j < 64*HID/4; j += 256) a4[j] = (f4)0.f;
    }

    const int l = tid & 63, w = tid >> 6;
    const int l16 = l & 15, quad = l >> 4;
    const int nt0 = 2*w, nt1 = 2*w + 1;
    const int c0 = nt0*16 + l16, c1c = nt1*16 + l16;

    {
        f4 acc[4][2];
        #pragma unroll
        for (int mt = 0; mt < 4; ++mt) { acc[mt][0] = (f4)0.f; acc[mt][1] = (f4)0.f; }
        #pragma unroll
        for (int kc = 0; kc < 8; ++kc) {
            s8 b0  = *(const s8*)(w1p + (((size_t)nt0*8 + kc)*64 + l)*8);
            s8 b1f = *(const s8*)(w1p + (((size_t)nt1*8 + kc)*64 + l)*8);
            #pragma unroll
            for (int mt = 0; mt < 4; ++mt) {
                s8 a = *(const s8*)&x[mt*16 + l16][kc*32 + quad*8];
                acc[mt][0] = __builtin_amdgcn_mfma_f32_16x16x32_bf16(a, b0,  acc[mt][0], 0, 0, 0);
                acc[mt][1] = __builtin_amdgcn_mfma_f32_16x16x32_bf16(a, b1f, acc[mt][1], 0, 0, 0);
            }
        }
        float bia0 = b1n[c0], bia1 = b1n[c1c];
        #pragma unroll
        for (int mt = 0; mt < 4; ++mt) {
            #pragma unroll
            for (int i = 0; i < 4; ++i) {
                int row = mt*16 + quad*4 + i;
                t1[row][c0]  = f2b(siluf(acc[mt][0][i] + bia0));
                t1[row][c1c] = f2b(siluf(acc[mt][1][i] + bia1));
            }
        }
    }
    __syncthreads();

    {
        f4 acc[4][2];
        #pragma unroll
        for (int mt = 0; mt < 4; ++mt) { acc[mt][0] = (f4)0.f; acc[mt][1] = (f4)0.f; }
        #pragma unroll
        for (int kc = 0; kc < 4; ++kc) {
            s8 b0  = *(const s8*)(w2p + (((size_t)nt0*4 + kc)*64 + l)*8);
            s8 b1f = *(const s8*)(w2p + (((size_t)nt1*4 + kc)*64 + l)*8);
            #pragma unroll
            for (int mt = 0; mt < 4; ++mt) {
                s8 a = *(const s8*)&t1[mt*16 + l16][kc*32 + quad*8];
                acc[mt][0] = __builtin_amdgcn_mfma_f32_16x16x32_bf16(a, b0,  acc[mt][0], 0, 0, 0);
                acc[mt][1] = __builtin_amdgcn_mfma_f32_16x16x32_bf16(a, b1f, acc[mt][1], 0, 0, 0);
            }
        }
        float bia0 = b2n[c0], bia1 = b2n[c1c];
        __syncthreads();
        #pragma unroll
        for (int mt = 0; mt < 4; ++mt) {
            #pragma unroll
            for (int i = 0; i < 4; ++i) {
                int row = mt*16 + quad*4 + i;
                hn[row][c0]  = acc[mt][0][i] + bia0;
                hn[row][c1c] = acc[mt][1][i] + bia1;
            }
        }
    }
    __syncthreads();

    {
        int r = tid >> 2, part = tid & 3;
        float s = 0.f, qv = 0.f;
        #pragma unroll
        for (int j = 0; j < 32; ++j) {
            float v = hn[r][part + 4*j];
            s += v; qv += v*v;
        }
        s += __shfl_xor(s, 1); qv += __shfl_xor(qv, 1);
        s += __shfl_xor(s, 2); qv += __shfl_xor(qv, 2);
        if (part == 0) {
            float mu = s * (1.0f/HID);
            float var = qv * (1.0f/HID) - mu*mu;
            mus[r] = mu;
            rstds[r] = rsqrtf(var + 1e-5f);
        }
    }
    __syncthreads();

    #pragma unroll
    for (int it = 0; it < 32; ++it) {
        int idx = it*256 + tid;
        int r = idx >> 7, c = idx & 127;
        float v = (hn[r][c] - mus[r]) * rstds[r] * lg[c] + lb[c];
        short s = f2b(v);
        hb[(long)(n0 + r)*HID + c] = s;
        t1[r][c] = s;
    }
    if (tid < 192) {
        int i = tid / 3, d = tid - i*3;
        int n = n0 + i;
        float dg = (float)(rowStart[n+1] - rowStart[n]);
        float np = pos[n*3+d] + upd[n*3+d] / (dg + 1e-6f);
        pos[n*3+d] = np;
        posS[i][d] = np;
        upd[n*3+d] = 0.f;
    }
    __syncthreads();

    if (wcatn) {
        f4 acc[4][4];
        #pragma unroll
        for (int mt = 0; mt < 4; ++mt)
            #pragma unroll
            for (int nt4 = 0; nt4 < 4; ++nt4) acc[mt][nt4] = (f4)0.f;
        #pragma unroll
        for (int kc = 0; kc < 4; ++kc) {
            s8 a[4];
            #pragma unroll
            for (int mt = 0; mt < 4; ++mt)
                a[mt] = *(const s8*)&t1[mt*16 + l16][kc*32 + quad*8];
            #pragma unroll
            for (int nt4 = 0; nt4 < 4; ++nt4) {
                int nt = w*4 + nt4;
                s8 b = *(const s8*)(wcatn + (((size_t)nt*4 + kc)*64 + l)*8);
                #pragma unroll
                for (int mt = 0; mt < 4; ++mt)
                    acc[mt][nt4] = __builtin_amdgcn_mfma_f32_16x16x32_bf16(a[mt], b, acc[mt][nt4], 0, 0, 0);
            }
        }
        #pragma unroll
        for (int nt4 = 0; nt4 < 4; ++nt4) {
            int col = (w*4 + nt4)*16 + l16;
            float bias = (col < 128) ? b1next[col] : 0.f;
            #pragma unroll
            for (int mt = 0; mt < 4; ++mt)
                #pragma unroll
                for (int i = 0; i < 4; ++i) {
                    int row = mt*16 + quad*4 + i;
                    H1[(long)(n0 + row)*256 + col] = f2b(acc[mt][nt4][i] + bias);
                }
        }
    } else {
        f4 acc[4];
        #pragma unroll
        for (int mt = 0; mt < 4; ++mt) acc[mt] = (f4)0.f;
        #pragma unroll
        for (int kc = 0; kc < 4; ++kc) {
            s8 b = *(const s8*)(hw1p + (((size_t)w*4 + kc)*64 + l)*8);
            #pragma unroll
            for (int mt = 0; mt < 4; ++mt) {
                s8 a = *(const s8*)&t1[mt*16 + l16][kc*32 + quad*8];
                acc[mt] = __builtin_amdgcn_mfma_f32_16x16x32_bf16(a, b, acc[mt], 0, 0, 0);
            }
        }
        int col = w*16 + l16;
        float bias = hb1[col];
        #pragma unroll
        for (int mt = 0; mt < 4; ++mt)
            #pragma unroll
            for (int i = 0; i < 4; ++i) {
                int row = mt*16 + quad*4 + i;
                hid[row][col] = siluf(acc[mt][i] + bias);
            }
        __syncthreads();
        if (tid < 192) {
            int r = tid / 3, cc = tid - r*3;
            float a2 = hb2[cc];
            #pragma unroll
            for (int k = 0; k < 64; ++k) a2 += hid[r][k] * hw2[k*3 + cc];
            int n = n0 + r;
            float v = posS[r][cc] + a2;
            if (flags[0]) ((__hip_bfloat16*)out)[n*3+cc] = __float2bfloat16(v);
            else          ((float*)out)[n*3+cc] = v;
        }
    }
}

// ---------------------------------------------------------------------------
extern "C" void kernel_launch(void* const* d_in, const int* in_sizes, int n_in,
                              void* d_out, int out_size, void* d_ws, size_t ws_size,
                              hipStream_t stream)
{
    (void)in_sizes; (void)n_in; (void)out_size; (void)ws_size;

    int* flags = (int*)d_ws;
    float* base = (float*)d_ws;
    size_t off = 64;
    auto alloc = [&](size_t n) { float* p = base + off; off += (n + 63) & ~63ull; return p; };

    static const int aidx[24] = {0,1,3,4,5,6,7,8,9,10,11,12,13,14,15,16,17,18,19,20,21,22,23,24};
    static const int alen[24] = {
        BB*LAT, NN*AF, NA*3, LAT*HID, HID, AF*HID, HID,
        NL*257*HID, NL*HID, NL*HID*HID, NL*HID,
        NL*256*HID, NL*HID, NL*HID*HID, NL*HID,
        NL*HID*HID, NL*HID, NL*HID, NL*HID, NL*HID,
        HID*64, 64, 64*3, 3
    };
    CvtDesc cd;
    float* fp[24];
    for (int a = 0; a < 24; ++a) {
        fp[a] = alloc((size_t)alen[a]);
        cd.src[a] = d_in[aidx[a]];
        cd.dst[a] = fp[a];
        cd.len[a] = alen[a];
    }
    float* agg = alloc((size_t)NN*HID);
    float* pos = alloc((size_t)NN*3);
    float* upd = alloc((size_t)NN*3);
    short* hb  = (short*)alloc((size_t)NN*HID/2);
    short* H1  = (short*)alloc((size_t)NN*256/2);
    short* wcatp = (short*)alloc((size_t)NL*32768/2);
    short* w2p = (short*)alloc((size_t)NL*16384/2);
    short* c1p = (short*)alloc((size_t)NL*16384/2);
    short* nw1p = (short*)alloc((size_t)NL*32768/2);
    short* nw2p = (short*)alloc((size_t)NL*16384/2);
    short* hw1p = (short*)alloc((size_t)8192/2);
    int* cnt      = (int*)alloc((size_t)NN);
    int* rowStart = (int*)alloc((size_t)NN + 1);
    int* cursor   = (int*)alloc((size_t)NN);
    int* rS       = (int*)alloc((size_t)NE);
    int* cS       = (int*)alloc((size_t)NE);
    const int* eidx = (const int*)d_in[2];

    k_detect<<<1, 256, 0, stream>>>((const unsigned short*)d_in[0],
                                    (const unsigned int*)d_in[2], flags);
    k_convert<<<dim3((NN*AF + 255)/256, 24), 256, 0, stream>>>(cd, flags);

    PackJobs pj;
    for (int l = 0; l < NL; ++l) {
        int b5 = l*5;
        pj.src[b5+0] = fp[7]  + (size_t)l*257*HID; pj.dst[b5+0] = wcatp + (size_t)l*32768; pj.K[b5+0] = 256; pj.mode[b5+0] = 1;
        pj.src[b5+1] = fp[9]  + (size_t)l*HID*HID; pj.dst[b5+1] = w2p   + (size_t)l*16384; pj.K[b5+1] = 128; pj.mode[b5+1] = 0;
        pj.src[b5+2] = fp[15] + (size_t)l*HID*HID; pj.dst[b5+2] = c1p   + (size_t)l*16384; pj.K[b5+2] = 128; pj.mode[b5+2] = 0;
        pj.src[b5+3] = fp[11] + (size_t)l*256*HID; pj.dst[b5+3] = nw1p  + (size_t)l*32768; pj.K[b5+3] = 256; pj.mode[b5+3] = 0;
        pj.src[b5+4] = fp[13] + (size_t)l*HID*HID; pj.dst[b5+4] = nw2p  + (size_t)l*16384; pj.K[b5+4] = 128; pj.mode[b5+4] = 0;
    }
    pj.src[10] = fp[20]; pj.dst[10] = hw1p; pj.K[10] = 128; pj.mode[10] = 2;
    k_packall<<<dim3(128, 11), 256, 0, stream>>>(pj);

    // counting sort edges by row
    hipMemsetAsync(cnt, 0, (size_t)NN*sizeof(int), stream);
    k_hist<<<(NE + 255)/256, 256, 0, stream>>>(eidx, flags, cnt);
    k_scan<<<1, 1024, 0, stream>>>(cnt, rowStart, cursor);
    k_scatter<<<(NE + 255)/256, 256, 0, stream>>>(eidx, flags, cursor, rS, cS);

    k_init3<<<NN/64, 256, 0, stream>>>(fp[0], fp[3], fp[4],
                                       fp[1], fp[5], fp[6], fp[2], pos, hb,
                                       wcatp, fp[8], H1, agg, upd);

    for (int l = 0; l < NL; ++l) {
        k_edge_os<<<NTILE, 256, 0, stream>>>(H1, rS, cS, pos,
            fp[7] + (size_t)l*257*HID + 256*HID,       // w1c (d2 row, f32)
            w2p + (size_t)l*16384, fp[10] + (size_t)l*HID,
            c1p + (size_t)l*16384, fp[16] + (size_t)l*HID,
            fp[17] + (size_t)l*HID,
            agg, upd);
        const short* wcatn = (l+1 < NL) ? (wcatp + (size_t)(l+1)*32768) : nullptr;
        const float* b1nx  = (l+1 < NL) ? (fp[8] + (size_t)(l+1)*HID) : fp[8];
        k_node_mfma<<<NN/64, 256, 0, stream>>>(hb, agg,
            nw1p + (size_t)l*32768, fp[12] + (size_t)l*HID,
            nw2p + (size_t)l*16384, fp[14] + (size_t)l*HID,
            fp[18] + (size_t)l*HID, fp[19] + (size_t)l*HID,
            pos, upd, rowStart, wcatn, b1nx, H1,
            hw1p, fp[21], fp[22], fp[23], d_out, flags);
    }
}

// Round 8
// 571.022 us; speedup vs baseline: 1.6862x; 1.1370x over previous
//
#include <hip/hip_runtime.h>
#include <hip/hip_bf16.h>

#define BB 512
#define NA 58
#define LAT 64
#define HID 128
#define AF 10
#define NL 2
#define NN (BB*NA)      // 29696
#define NE (NN*16)      // 475136
#define ET 64           // edges per tile
#define NTILE (NE/ET)   // 7424

typedef __attribute__((ext_vector_type(8))) short s8;
typedef __attribute__((ext_vector_type(4))) float f4;

struct CvtDesc {
    const void* src[24];
    float*      dst[24];
    int         len[24];
};

struct PackJobs {
    const float* src[11];
    short*       dst[11];
    int          K[11];
    int          mode[11];   // 0: [K][128] B-frag; 1: edge-w1 concat; 2: [K][64] B-frag
};

__device__ __forceinline__ float siluf(float x) {
    return x * __builtin_amdgcn_rcpf(1.0f + __expf(-x));
}

__device__ __forceinline__ short f2b(float x) {
    __hip_bfloat16 b = __float2bfloat16(x);
    return *(short*)&b;
}

__device__ __forceinline__ float b2f(short s) {
    return __uint_as_float(((unsigned int)(unsigned short)s) << 16);
}

// ---------------------------------------------------------------------------
__global__ void k_detect(const unsigned short* __restrict__ z16,
                         const unsigned int* __restrict__ e32,
                         int* __restrict__ flags) {
    __shared__ int sbf, si64;
    if (threadIdx.x == 0) { sbf = 0; si64 = 0; }
    __syncthreads();
    int c1 = 0, c2 = 0;
    for (int i = threadIdx.x; i < 1024; i += 256) {
        unsigned short v = z16[2*i];
        int e = (v >> 7) & 0xFF;
        if (e >= 100 && e <= 140) c1++;
        if (e32[2*i + 1] == 0u) c2++;
    }
    atomicAdd(&sbf, c1);
    atomicAdd(&si64, c2);
    __syncthreads();
    if (threadIdx.x == 0) {
        flags[0] = (sbf  > 600) ? 1 : 0;
        flags[1] = (si64 > 600) ? 1 : 0;
    }
}

__global__ void k_convert(CvtDesc d, const int* __restrict__ flags) {
    int a = blockIdx.y;
    int i = blockIdx.x * blockDim.x + threadIdx.x;
    int n = d.len[a];
    if (i >= n) return;
    if (flags[0]) {
        d.dst[a][i] = __bfloat162float(((const __hip_bfloat16*)d.src[a])[i]);
    } else {
        d.dst[a][i] = ((const float*)d.src[a])[i];
    }
}

__global__ void k_packall(PackJobs pj) {
    int j = blockIdx.y;
    int idx = blockIdx.x * 256 + threadIdx.x;
    const float* w = pj.src[j];
    short* o = pj.dst[j];
    int mode = pj.mode[j];
    if (mode == 0) {
        int K = pj.K[j];
        if (idx >= 128*K) return;
        int jj = idx & 7;
        int l  = (idx >> 3) & 63;
        int rest = idx >> 9;
        int KC = K >> 5;
        int kc = rest % KC;
        int nt = rest / KC;
        int n = nt*16 + (l & 15);
        int k = kc*32 + (l >> 4)*8 + jj;
        o[idx] = f2b(w[k*128 + n]);
    } else if (mode == 1) {
        if (idx >= 32768) return;
        int jj = idx & 7;
        int l  = (idx >> 3) & 63;
        int rest = idx >> 9;
        int kc = rest & 3;
        int nt = rest >> 2;
        int n = nt*16 + (l & 15);
        int k = kc*32 + (l >> 4)*8 + jj;
        float v = (n < 128) ? w[k*128 + n] : w[(128 + k)*128 + (n - 128)];
        o[idx] = f2b(v);
    } else {
        if (idx >= 8192) return;
        int jj = idx & 7;
        int l  = (idx >> 3) & 63;
        int rest = idx >> 9;
        int kc = rest & 3;
        int nt = rest >> 2;
        int n = nt*16 + (l & 15);
        int k = kc*32 + (l >> 4)*8 + jj;
        o[idx] = f2b(w[k*64 + n]);
    }
}

// ---------------------------------------------------------------------------
__global__ void k_hist(const int* __restrict__ eidx, const int* __restrict__ flags,
                       int* __restrict__ cnt) {
    int e = blockIdx.x * 256 + threadIdx.x;
    if (e >= NE) return;
    int is64 = flags[1];
    int r = eidx[is64 ? 2*(long)e : (long)e];
    atomicAdd(&cnt[r], 1);
}

__global__ __launch_bounds__(1024) void k_scan(const int* __restrict__ cnt,
                                               int* __restrict__ rowStart,
                                               int* __restrict__ cursor) {
    __shared__ int part[1024];
    int t = threadIdx.x;
    int base = t * 29;                    // NN == 1024*29
    int loc[29];
    int s = 0;
    #pragma unroll
    for (int i = 0; i < 29; ++i) { loc[i] = s; s += cnt[base + i]; }
    part[t] = s;
    __syncthreads();
    for (int d = 1; d < 1024; d <<= 1) {
        int v = (t >= d) ? part[t - d] : 0;
        __syncthreads();
        part[t] += v;
        __syncthreads();
    }
    int pre = (t == 0) ? 0 : part[t - 1];
    #pragma unroll
    for (int i = 0; i < 29; ++i) {
        int v = pre + loc[i];
        rowStart[base + i] = v;
        cursor[base + i] = v;
    }
    if (t == 1023) rowStart[NN] = pre + s;
}

__global__ void k_scatter(const int* __restrict__ eidx, const int* __restrict__ flags,
                          int* __restrict__ cursor,
                          int* __restrict__ rS, int* __restrict__ cS) {
    int e = blockIdx.x * 256 + threadIdx.x;
    if (e >= NE) return;
    int is64 = flags[1];
    long ge = e, gc = (long)e + NE;
    int r = eidx[is64 ? 2*ge : ge];
    int c = eidx[is64 ? 2*gc : gc];
    int p = atomicAdd(&cursor[r], 1);
    rS[p] = r; cS[p] = c;
}

// ---------------------------------------------------------------------------
// init3: fused hz GEMV + h init (bf16) + pos init + zero agg/upd + H1(l0) GEMM.
__global__ __launch_bounds__(256) void k_init3(
    const float* __restrict__ z, const float* __restrict__ lw,
    const float* __restrict__ lbz,
    const float* __restrict__ at,
    const float* __restrict__ aw, const float* __restrict__ ab,
    const float* __restrict__ ic,
    float* __restrict__ pos, short* __restrict__ hb,
    const short* __restrict__ wcat0, const float* __restrict__ b10,
    short* __restrict__ H1, float* __restrict__ agg, float* __restrict__ upd)
{
    __shared__ short x[64][136];
    __shared__ float awS[AF][HID];
    __shared__ float atS[64][AF+2];
    __shared__ float zbS[3][LAT];
    __shared__ float hzS[3][HID];
    const int tid = threadIdx.x;
    const int n0 = blockIdx.x * 64;
    const int b0 = n0 / NA;
    const int nb = (n0 + 63) / NA - b0 + 1;   // 1..3

    for (int i = tid; i < AF*HID; i += 256) awS[i/HID][i%HID] = aw[i];
    for (int i = tid; i < 64*AF; i += 256)
        atS[i/AF][i%AF] = at[(long)(n0 + i/AF)*AF + i%AF];
    for (int i = tid; i < nb*LAT; i += 256) {
        int bi = i / LAT, k = i - bi*LAT;
        int bidx = b0 + bi;
        zbS[bi][k] = (bidx < BB) ? z[bidx*LAT + k] : 0.f;
    }
    __syncthreads();

    for (int i = tid; i < nb*HID; i += 256) {
        int bi = i / HID, c = i - bi*HID;
        float acc = lbz[c];
        #pragma unroll
        for (int k = 0; k < LAT; ++k) acc += zbS[bi][k] * lw[k*HID + c];
        hzS[bi][c] = acc;
    }
    __syncthreads();

    #pragma unroll
    for (int it = 0; it < 32; ++it) {
        int idx = it*256 + tid;
        int r = idx >> 7, c = idx & 127;
        int n = n0 + r;
        float v = hzS[n/NA - b0][c] + ab[c];
        #pragma unroll
        for (int f = 0; f < AF; ++f) v += atS[r][f]*awS[f][c];
        short s = f2b(v);
        x[r][c] = s;
        hb[(long)n*HID + c] = s;
    }
    if (tid < 192) {
        int i = tid/3, d = tid - i*3;
        int n = n0 + i;
        pos[n*3 + d] = ic[(n % NA)*3 + d];
        upd[n*3 + d] = 0.f;
    }
    {
        f4* a4 = (f4*)(agg + (long)n0*HID);
        for (int j = tid; j < 64*HID/4; j += 256) a4[j] = (f4)0.f;
    }
    __syncthreads();

    const int l = tid & 63, w = tid >> 6;
    const int l16 = l & 15, quad = l >> 4;
    f4 acc[4][4];
    #pragma unroll
    for (int mt = 0; mt < 4; ++mt)
        #pragma unroll
        for (int nt4 = 0; nt4 < 4; ++nt4) acc[mt][nt4] = (f4)0.f;
    #pragma unroll
    for (int kc = 0; kc < 4; ++kc) {
        s8 a[4];
        #pragma unroll
        for (int mt = 0; mt < 4; ++mt)
            a[mt] = *(const s8*)&x[mt*16 + l16][kc*32 + quad*8];
        #pragma unroll
        for (int nt4 = 0; nt4 < 4; ++nt4) {
            int nt = w*4 + nt4;
            s8 b = *(const s8*)(wcat0 + (((size_t)nt*4 + kc)*64 + l)*8);
            #pragma unroll
            for (int mt = 0; mt < 4; ++mt)
                acc[mt][nt4] = __builtin_amdgcn_mfma_f32_16x16x32_bf16(a[mt], b, acc[mt][nt4], 0, 0, 0);
        }
    }
    #pragma unroll
    for (int nt4 = 0; nt4 < 4; ++nt4) {
        int col = (w*4 + nt4)*16 + l16;
        float bias = (col < 128) ? b10[col] : 0.f;
        #pragma unroll
        for (int mt = 0; mt < 4; ++mt)
            #pragma unroll
            for (int i = 0; i < 4; ++i) {
                int row = mt*16 + quad*4 + i;
                H1[(long)(n0 + row)*256 + col] = f2b(acc[mt][nt4][i] + bias);
            }
    }
}

// ---------------------------------------------------------------------------
// Edge kernel v15 (resubmit — R7 bench was an infra failure, no data):
// one-shot + aliased mm (LDS 18.4K, R6) + STREAMED B-fragments.
// R6 evidence: 8-block concurrency works (59% occ) but preloaded w2f/c1f
// (64 regs) spilled under the (256,6) cap. Fix the footprint, not the cap:
// fragments are loaded depth-2 inside the MFMA loops from the 16KB L2-hot
// w2p/c1p (identical for all 7424 blocks); bias/cw scalars load at use sites.
// Peak liveness ~ acc(32) + frags(16) + misc ≈ 75 — fits the non-binding
// (256,3) cap of 84 with zero spill; real total (V+A) drops ~124→~75.
__global__ __launch_bounds__(256, 3) void k_edge_os(
    const short* __restrict__ H1,
    const int* __restrict__ rS, const int* __restrict__ cS,
    const float* __restrict__ pos,
    const float* __restrict__ w1c,
    const short* __restrict__ w2p, const float* __restrict__ b2,
    const short* __restrict__ c1p, const float* __restrict__ cb1,
    const float* __restrict__ cw2,
    float* __restrict__ agg, float* __restrict__ upd)
{
    __shared__ short t1[ET][136];        // doubles as mm after barrier (A2)
    __shared__ int   rIs[ET], cIs[ET];
    __shared__ float sred[ET];

    const int tid = threadIdx.x;
    const int l = tid & 63, w = tid >> 6;
    const int l16 = l & 15, quad = l >> 4;
    const int c0 = (2*w)*16 + l16, c1c = (2*w+1)*16 + l16;
    const int half = tid >> 7, ch = tid & 127;
    const int q = tid & 15;
    const int esub = tid >> 4;
    const int T = blockIdx.x;

    float wv[8];
    #pragma unroll
    for (int j = 0; j < 8; ++j) wv[j] = w1c[q*8 + j];

    // PREIDX + build t1 for this block's single tile
    const long eb = (long)T * ET;
    if (tid < ET) sred[tid] = 0.f;
    #pragma unroll
    for (int it = 0; it < 4; ++it) {
        int e = esub + 16*it;
        int r = rS[eb + e], c = cS[eb + e];
        float rx = pos[r*3+0] - pos[c*3+0];
        float ry = pos[r*3+1] - pos[c*3+1];
        float rz = pos[r*3+2] - pos[c*3+2];
        float d2 = fminf(fmaxf(rx*rx + ry*ry + rz*rz, 1e-6f), 1e6f);
        s8 va = *(const s8*)(H1 + (long)r*256 + q*8);
        s8 vb = *(const s8*)(H1 + (long)c*256 + 128 + q*8);
        s8 o;
        #pragma unroll
        for (int j = 0; j < 8; ++j)
            o[j] = f2b(siluf(b2f(va[j]) + b2f(vb[j]) + d2*wv[j]));
        *(s8*)&t1[e][q*8] = o;
        if (q == 0) { rIs[e] = r; cIs[e] = c; }
    }
    __syncthreads();                     // (A) t1 + meta ready

    // stage2 MFMA — fragments streamed depth-2 from L2-resident w2p.
    // frag(colTile nt, kc) lives at w2p + ((nt*4 + kc)*64 + l)*8 shorts;
    // per-kc stride = 512 shorts.
    f4 acc[4][2];
    #pragma unroll
    for (int mt = 0; mt < 4; ++mt) { acc[mt][0] = (f4)0.f; acc[mt][1] = (f4)0.f; }
    {
        const short* wb0 = w2p + ((size_t)(2*w)*4*64 + l)*8;
        const short* wb1 = w2p + ((size_t)(2*w+1)*4*64 + l)*8;
        s8 b0 = *(const s8*)wb0;
        s8 b1 = *(const s8*)wb1;
        #pragma unroll
        for (int it = 0; it < 4; ++it) {
            s8 nb0 = b0, nb1 = b1;
            if (it < 3) {
                nb0 = *(const s8*)(wb0 + (size_t)(it+1)*512);
                nb1 = *(const s8*)(wb1 + (size_t)(it+1)*512);
            }
            #pragma unroll
            for (int mt = 0; mt < 4; ++mt) {
                s8 a = *(const s8*)&t1[mt*16 + l16][it*32 + quad*8];
                acc[mt][0] = __builtin_amdgcn_mfma_f32_16x16x32_bf16(a, b0, acc[mt][0], 0, 0, 0);
                acc[mt][1] = __builtin_amdgcn_mfma_f32_16x16x32_bf16(a, b1, acc[mt][1], 0, 0, 0);
            }
            b0 = nb0; b1 = nb1;
        }
    }
    __syncthreads();                     // (A2) all t1 reads done — safe to overwrite

    // mm epilogue written into t1's space; biases loaded at use (L2-hot 512B)
    short (*mm)[136] = t1;
    {
        const float bia2_0 = b2[c0], bia2_1 = b2[c1c];
        #pragma unroll
        for (int mt = 0; mt < 4; ++mt) {
            #pragma unroll
            for (int i = 0; i < 4; ++i) {
                int row = mt*16 + quad*4 + i;
                mm[row][c0]  = f2b(siluf(acc[mt][0][i] + bia2_0));
                mm[row][c1c] = f2b(siluf(acc[mt][1][i] + bia2_1));
            }
        }
    }
    __syncthreads();                     // (B) mm ready

    // agg: run-length dedup over sorted rows, atomics drain under stage3
    {
        int e0 = half * 32;
        int cur = rIs[e0];
        float a = 0.f;
        #pragma unroll
        for (int e = e0; e < e0 + 32; ++e) {
            int r = rIs[e];
            if (r != cur) {
                atomicAdd(&agg[(long)cur*HID + ch], a);
                a = 0.f; cur = r;
            }
            a += b2f(mm[e][ch]);
        }
        atomicAdd(&agg[(long)cur*HID + ch], a);
    }
    // stage3 — fragments streamed depth-2 from L2-resident c1p
    {
        f4 acc3[4][2];
        #pragma unroll
        for (int mt = 0; mt < 4; ++mt) { acc3[mt][0] = (f4)0.f; acc3[mt][1] = (f4)0.f; }
        const short* cb0 = c1p + ((size_t)(2*w)*4*64 + l)*8;
        const short* cb1p_ = c1p + ((size_t)(2*w+1)*4*64 + l)*8;
        s8 b0 = *(const s8*)cb0;
        s8 b1 = *(const s8*)cb1p_;
        #pragma unroll
        for (int kc = 0; kc < 4; ++kc) {
            s8 nb0 = b0, nb1 = b1;
            if (kc < 3) {
                nb0 = *(const s8*)(cb0 + (size_t)(kc+1)*512);
                nb1 = *(const s8*)(cb1p_ + (size_t)(kc+1)*512);
            }
            #pragma unroll
            for (int mt = 0; mt < 4; ++mt) {
                s8 a = *(const s8*)&mm[mt*16 + l16][kc*32 + quad*8];
                acc3[mt][0] = __builtin_amdgcn_mfma_f32_16x16x32_bf16(a, b0, acc3[mt][0], 0, 0, 0);
                acc3[mt][1] = __builtin_amdgcn_mfma_f32_16x16x32_bf16(a, b1, acc3[mt][1], 0, 0, 0);
            }
            b0 = nb0; b1 = nb1;
        }
        const float biac_0 = cb1[c0], biac_1 = cb1[c1c];
        const float cw0    = cw2[c0], cw1v   = cw2[c1c];
        #pragma unroll
        for (int mt = 0; mt < 4; ++mt) {
            #pragma unroll
            for (int i = 0; i < 4; ++i) {
                float p = siluf(acc3[mt][0][i] + biac_0) * cw0
                        + siluf(acc3[mt][1][i] + biac_1) * cw1v;
                p += __shfl_xor(p, 1);
                p += __shfl_xor(p, 2);
                p += __shfl_xor(p, 4);
                p += __shfl_xor(p, 8);
                if (l16 == 0) {
                    int row = mt*16 + quad*4 + i;
                    atomicAdd(&sred[row], p);
                }
            }
        }
    }
    // upd operands (rIs/cIs stable — single tile)
    int   ur = 0;
    float urx = 0.f, ury = 0.f, urz = 0.f;
    if (tid < ET) {
        ur = rIs[tid];
        int uc = cIs[tid];
        urx = pos[ur*3+0] - pos[uc*3+0];
        ury = pos[ur*3+1] - pos[uc*3+1];
        urz = pos[ur*3+2] - pos[uc*3+2];
    }
    __syncthreads();                     // (C) sred complete

    if (tid < ET) {
        float cwv = fminf(fmaxf(sred[tid], -1.f), 1.f);
        atomicAdd(&upd[ur*3+0], cwv*urx);
        atomicAdd(&upd[ur*3+1], cwv*ury);
        atomicAdd(&upd[ur*3+2], cwv*urz);
    }
}

// ---------------------------------------------------------------------------
// Node kernel + fused H1(next layer) or fused head (last layer).
__global__ __launch_bounds__(256) void k_node_mfma(
    short* __restrict__ hb, float* __restrict__ agg,
    const short* __restrict__ w1p, const float* __restrict__ b1n,
    const short* __restrict__ w2p, const float* __restrict__ b2n,
    const float* __restrict__ lg, const float* __restrict__ lb,
    float* __restrict__ pos, float* __restrict__ upd,
    const int* __restrict__ rowStart,
    const short* __restrict__ wcatn, const float* __restrict__ b1next,
    short* __restrict__ H1,
    const short* __restrict__ hw1p, const float* __restrict__ hb1,
    const float* __restrict__ hw2, const float* __restrict__ hb2,
    void* __restrict__ out, const int* __restrict__ flags)
{
    __shared__ short x[64][264];
    __shared__ short t1[64][144];
    __shared__ float mus[64], rstds[64];
    __shared__ float posS[64][3];
    float (*hn)[132] = (float (*)[132])&x[0][0];
    float (*hid)[68] = (float (*)[68])&x[0][0];

    const int tid = threadIdx.x;
    const int n0 = blockIdx.x * 64;

    #pragma unroll
    for (int it = 0; it < 4; ++it) {
        int idx = it*256 + tid;
        int e = idx >> 4, qq = idx & 15;
        *(int4*)&x[e][qq*8] = *(const int4*)(hb + (long)(n0+e)*HID + qq*8);
    }
    #pragma unroll
    for (int it = 0; it < 8; ++it) {
        int idx = it*256 + tid;
        int e = idx >> 5, qq = idx & 31;
        float4 v = *(const float4*)(agg + (long)(n0+e)*HID + qq*4);
        short4 sv;
        sv.x = f2b(v.x); sv.y = f2b(v.y); sv.z = f2b(v.z); sv.w = f2b(v.w);
        *(short4*)&x[e][128 + qq*4] = sv;
    }
    __syncthreads();

    {
        f4* a4 = (f4*)(agg + (long)n0*HID);
        for (int j = tid; j < 64*HID/4; j += 256) a4[j] = (f4)0.f;
    }

    const int l = tid & 63, w = tid >> 6;
    const int l16 = l & 15, quad = l >> 4;
    const int nt0 = 2*w, nt1 = 2*w + 1;
    const int c0 = nt0*16 + l16, c1c = nt1*16 + l16;

    {
        f4 acc[4][2];
        #pragma unroll
        for (int mt = 0; mt < 4; ++mt) { acc[mt][0] = (f4)0.f; acc[mt][1] = (f4)0.f; }
        #pragma unroll
        for (int kc = 0; kc < 8; ++kc) {
            s8 b0  = *(const s8*)(w1p + (((size_t)nt0*8 + kc)*64 + l)*8);
            s8 b1f = *(const s8*)(w1p + (((size_t)nt1*8 + kc)*64 + l)*8);
            #pragma unroll
            for (int mt = 0; mt < 4; ++mt) {
                s8 a = *(const s8*)&x[mt*16 + l16][kc*32 + quad*8];
                acc[mt][0] = __builtin_amdgcn_mfma_f32_16x16x32_bf16(a, b0,  acc[mt][0], 0, 0, 0);
                acc[mt][1] = __builtin_amdgcn_mfma_f32_16x16x32_bf16(a, b1f, acc[mt][1], 0, 0, 0);
            }
        }
        float bia0 = b1n[c0], bia1 = b1n[c1c];
        #pragma unroll
        for (int mt = 0; mt < 4; ++mt) {
            #pragma unroll
            for (int i = 0; i < 4; ++i) {
                int row = mt*16 + quad*4 + i;
                t1[row][c0]  = f2b(siluf(acc[mt][0][i] + bia0));
                t1[row][c1c] = f2b(siluf(acc[mt][1][i] + bia1));
            }
        }
    }
    __syncthreads();

    {
        f4 acc[4][2];
        #pragma unroll
        for (int mt = 0; mt < 4; ++mt) { acc[mt][0] = (f4)0.f; acc[mt][1] = (f4)0.f; }
        #pragma unroll
        for (int kc = 0; kc < 4; ++kc) {
            s8 b0  = *(const s8*)(w2p + (((size_t)nt0*4 + kc)*64 + l)*8);
            s8 b1f = *(const s8*)(w2p + (((size_t)nt1*4 + kc)*64 + l)*8);
            #pragma unroll
            for (int mt = 0; mt < 4; ++mt) {
                s8 a = *(const s8*)&t1[mt*16 + l16][kc*32 + quad*8];
                acc[mt][0] = __builtin_amdgcn_mfma_f32_16x16x32_bf16(a, b0,  acc[mt][0], 0, 0, 0);
                acc[mt][1] = __builtin_amdgcn_mfma_f32_16x16x32_bf16(a, b1f, acc[mt][1], 0, 0, 0);
            }
        }
        float bia0 = b2n[c0], bia1 = b2n[c1c];
        __syncthreads();
        #pragma unroll
        for (int mt = 0; mt < 4; ++mt) {
            #pragma unroll
            for (int i = 0; i < 4; ++i) {
                int row = mt*16 + quad*4 + i;
                hn[row][c0]  = acc[mt][0][i] + bia0;
                hn[row][c1c] = acc[mt][1][i] + bia1;
            }
        }
    }
    __syncthreads();

    {
        int r = tid >> 2, part = tid & 3;
        float s = 0.f, qv = 0.f;
        #pragma unroll
        for (int j = 0; j < 32; ++j) {
            float v = hn[r][part + 4*j];
            s += v; qv += v*v;
        }
        s += __shfl_xor(s, 1); qv += __shfl_xor(qv, 1);
        s += __shfl_xor(s, 2); qv += __shfl_xor(qv, 2);
        if (part == 0) {
            float mu = s * (1.0f/HID);
            float var = qv * (1.0f/HID) - mu*mu;
            mus[r] = mu;
            rstds[r] = rsqrtf(var + 1e-5f);
        }
    }
    __syncthreads();

    #pragma unroll
    for (int it = 0; it < 32; ++it) {
        int idx = it*256 + tid;
        int r = idx >> 7, c = idx & 127;
        float v = (hn[r][c] - mus[r]) * rstds[r] * lg[c] + lb[c];
        short s = f2b(v);
        hb[(long)(n0 + r)*HID + c] = s;
        t1[r][c] = s;
    }
    if (tid < 192) {
        int i = tid / 3, d = tid - i*3;
        int n = n0 + i;
        float dg = (float)(rowStart[n+1] - rowStart[n]);
        float np = pos[n*3+d] + upd[n*3+d] / (dg + 1e-6f);
        pos[n*3+d] = np;
        posS[i][d] = np;
        upd[n*3+d] = 0.f;
    }
    __syncthreads();

    if (wcatn) {
        f4 acc[4][4];
        #pragma unroll
        for (int mt = 0; mt < 4; ++mt)
            #pragma unroll
            for (int nt4 = 0; nt4 < 4; ++nt4) acc[mt][nt4] = (f4)0.f;
        #pragma unroll
        for (int kc = 0; kc < 4; ++kc) {
            s8 a[4];
            #pragma unroll
            for (int mt = 0; mt < 4; ++mt)
                a[mt] = *(const s8*)&t1[mt*16 + l16][kc*32 + quad*8];
            #pragma unroll
            for (int nt4 = 0; nt4 < 4; ++nt4) {
                int nt = w*4 + nt4;
                s8 b = *(const s8*)(wcatn + (((size_t)nt*4 + kc)*64 + l)*8);
                #pragma unroll
                for (int mt = 0; mt < 4; ++mt)
                    acc[mt][nt4] = __builtin_amdgcn_mfma_f32_16x16x32_bf16(a[mt], b, acc[mt][nt4], 0, 0, 0);
            }
        }
        #pragma unroll
        for (int nt4 = 0; nt4 < 4; ++nt4) {
            int col = (w*4 + nt4)*16 + l16;
            float bias = (col < 128) ? b1next[col] : 0.f;
            #pragma unroll
            for (int mt = 0; mt < 4; ++mt)
                #pragma unroll
                for (int i = 0; i < 4; ++i) {
                    int row = mt*16 + quad*4 + i;
                    H1[(long)(n0 + row)*256 + col] = f2b(acc[mt][nt4][i] + bias);
                }
        }
    } else {
        f4 acc[4];
        #pragma unroll
        for (int mt = 0; mt < 4; ++mt) acc[mt] = (f4)0.f;
        #pragma unroll
        for (int kc = 0; kc < 4; ++kc) {
            s8 b = *(const s8*)(hw1p + (((size_t)w*4 + kc)*64 + l)*8);
            #pragma unroll
            for (int mt = 0; mt < 4; ++mt) {
                s8 a = *(const s8*)&t1[mt*16 + l16][kc*32 + quad*8];
                acc[mt] = __builtin_amdgcn_mfma_f32_16x16x32_bf16(a, b, acc[mt], 0, 0, 0);
            }
        }
        int col = w*16 + l16;
        float bias = hb1[col];
        #pragma unroll
        for (int mt = 0; mt < 4; ++mt)
            #pragma unroll
            for (int i = 0; i < 4; ++i) {
                int row = mt*16 + quad*4 + i;
                hid[row][col] = siluf(acc[mt][i] + bias);
            }
        __syncthreads();
        if (tid < 192) {
            int r = tid / 3, cc = tid - r*3;
            float a2 = hb2[cc];
            #pragma unroll
            for (int k = 0; k < 64; ++k) a2 += hid[r][k] * hw2[k*3 + cc];
            int n = n0 + r;
            float v = posS[r][cc] + a2;
            if (flags[0]) ((__hip_bfloat16*)out)[n*3+cc] = __float2bfloat16(v);
            else          ((float*)out)[n*3+cc] = v;
        }
    }
}

// ---------------------------------------------------------------------------
extern "C" void kernel_launch(void* const* d_in, const int* in_sizes, int n_in,
                              void* d_out, int out_size, void* d_ws, size_t ws_size,
                              hipStream_t stream)
{
    (void)in_sizes; (void)n_in; (void)out_size; (void)ws_size;

    int* flags = (int*)d_ws;
    float* base = (float*)d_ws;
    size_t off = 64;
    auto alloc = [&](size_t n) { float* p = base + off; off += (n + 63) & ~63ull; return p; };

    static const int aidx[24] = {0,1,3,4,5,6,7,8,9,10,11,12,13,14,15,16,17,18,19,20,21,22,23,24};
    static const int alen[24] = {
        BB*LAT, NN*AF, NA*3, LAT*HID, HID, AF*HID, HID,
        NL*257*HID, NL*HID, NL*HID*HID, NL*HID,
        NL*256*HID, NL*HID, NL*HID*HID, NL*HID,
        NL*HID*HID, NL*HID, NL*HID, NL*HID, NL*HID,
        HID*64, 64, 64*3, 3
    };
    CvtDesc cd;
    float* fp[24];
    for (int a = 0; a < 24; ++a) {
        fp[a] = alloc((size_t)alen[a]);
        cd.src[a] = d_in[aidx[a]];
        cd.dst[a] = fp[a];
        cd.len[a] = alen[a];
    }
    float* agg = alloc((size_t)NN*HID);
    float* pos = alloc((size_t)NN*3);
    float* upd = alloc((size_t)NN*3);
    short* hb  = (short*)alloc((size_t)NN*HID/2);
    short* H1  = (short*)alloc((size_t)NN*256/2);
    short* wcatp = (short*)alloc((size_t)NL*32768/2);
    short* w2p = (short*)alloc((size_t)NL*16384/2);
    short* c1p = (short*)alloc((size_t)NL*16384/2);
    short* nw1p = (short*)alloc((size_t)NL*32768/2);
    short* nw2p = (short*)alloc((size_t)NL*16384/2);
    short* hw1p = (short*)alloc((size_t)8192/2);
    int* cnt      = (int*)alloc((size_t)NN);
    int* rowStart = (int*)alloc((size_t)NN + 1);
    int* cursor   = (int*)alloc((size_t)NN);
    int* rS       = (int*)alloc((size_t)NE);
    int* cS       = (int*)alloc((size_t)NE);
    const int* eidx = (const int*)d_in[2];

    k_detect<<<1, 256, 0, stream>>>((const unsigned short*)d_in[0],
                                    (const unsigned int*)d_in[2], flags);
    k_convert<<<dim3((NN*AF + 255)/256, 24), 256, 0, stream>>>(cd, flags);

    PackJobs pj;
    for (int l = 0; l < NL; ++l) {
        int b5 = l*5;
        pj.src[b5+0] = fp[7]  + (size_t)l*257*HID; pj.dst[b5+0] = wcatp + (size_t)l*32768; pj.K[b5+0] = 256; pj.mode[b5+0] = 1;
        pj.src[b5+1] = fp[9]  + (size_t)l*HID*HID; pj.dst[b5+1] = w2p   + (size_t)l*16384; pj.K[b5+1] = 128; pj.mode[b5+1] = 0;
        pj.src[b5+2] = fp[15] + (size_t)l*HID*HID; pj.dst[b5+2] = c1p   + (size_t)l*16384; pj.K[b5+2] = 128; pj.mode[b5+2] = 0;
        pj.src[b5+3] = fp[11] + (size_t)l*256*HID; pj.dst[b5+3] = nw1p  + (size_t)l*32768; pj.K[b5+3] = 256; pj.mode[b5+3] = 0;
        pj.src[b5+4] = fp[13] + (size_t)l*HID*HID; pj.dst[b5+4] = nw2p  + (size_t)l*16384; pj.K[b5+4] = 128; pj.mode[b5+4] = 0;
    }
    pj.src[10] = fp[20]; pj.dst[10] = hw1p; pj.K[10] = 128; pj.mode[10] = 2;
    k_packall<<<dim3(128, 11), 256, 0, stream>>>(pj);

    // counting sort edges by row
    hipMemsetAsync(cnt, 0, (size_t)NN*sizeof(int), stream);
    k_hist<<<(NE + 255)/256, 256, 0, stream>>>(eidx, flags, cnt);
    k_scan<<<1, 1024, 0, stream>>>(cnt, rowStart, cursor);
    k_scatter<<<(NE + 255)/256, 256, 0, stream>>>(eidx, flags, cursor, rS, cS);

    k_init3<<<NN/64, 256, 0, stream>>>(fp[0], fp[3], fp[4],
                                       fp[1], fp[5], fp[6], fp[2], pos, hb,
                                       wcatp, fp[8], H1, agg, upd);

    for (int l = 0; l < NL; ++l) {
        k_edge_os<<<NTILE, 256, 0, stream>>>(H1, rS, cS, pos,
            fp[7] + (size_t)l*257*HID + 256*HID,       // w1c (d2 row, f32)
            w2p + (size_t)l*16384, fp[10] + (size_t)l*HID,
            c1p + (size_t)l*16384, fp[16] + (size_t)l*HID,
            fp[17] + (size_t)l*HID,
            agg, upd);
        const short* wcatn = (l+1 < NL) ? (wcatp + (size_t)(l+1)*32768) : nullptr;
        const float* b1nx  = (l+1 < NL) ? (fp[8] + (size_t)(l+1)*HID) : fp[8];
        k_node_mfma<<<NN/64, 256, 0, stream>>>(hb, agg,
            nw1p + (size_t)l*32768, fp[12] + (size_t)l*HID,
            nw2p + (size_t)l*16384, fp[14] + (size_t)l*HID,
            fp[18] + (size_t)l*HID, fp[19] + (size_t)l*HID,
            pos, upd, rowStart, wcatn, b1nx, H1,
            hw1p, fp[21], fp[22], fp[23], d_out, flags);
    }
}